// Round 5
// baseline (2295.243 us; speedup 1.0000x reference)
//
#include <hip/hip_runtime.h>

// ---------------------------------------------------------------------------
// PerceiverResampler forward, MI355X gfx950.
// R5: ff1 back to 128x128 kernel (8-phase 256^2 regressed at 144 blocks /
//     K=1024 short loop); single transpose_all kernel per layer;
//     kv stays on 256^2 8-phase (554 TF vs 480 on 128^2).
// Residual stream (lat) lives in d_out (f32). Workspace ~261 MB.
// ---------------------------------------------------------------------------

typedef __attribute__((ext_vector_type(4))) float f32x4;
typedef __attribute__((ext_vector_type(8))) __bf16 bf16x8;
typedef __attribute__((ext_vector_type(4))) __bf16 bf16x4;

#define BATCH 32
#define SEQL  512
#define DIM   1024
#define HEADS 16
#define DH    64
#define LTOT  68          // 4 mean-pool latents + 64 learned
#define KEYS  580         // SEQL + LTOT
#define KPAD  640         // KEYS padded to 5*128
#define HID   4096
#define LN_EPS 1e-5f

__device__ __forceinline__ float bf2f(__bf16 v) { return (float)v; }
__device__ __forceinline__ __bf16 f2bf(float v) { return (__bf16)v; }

// async 16B global -> LDS (wave-uniform LDS base + lane*16)
__device__ __forceinline__ void gld_lds16(const __bf16* g, __bf16* l) {
    __builtin_amdgcn_global_load_lds(
        (const __attribute__((address_space(1))) void*)g,
        (__attribute__((address_space(3))) void*)l, 16, 0, 0);
}

#define SBAR()   asm volatile("s_barrier" ::: "memory")
#define VMCNT4() asm volatile("s_waitcnt vmcnt(4)" ::: "memory")

// ---------------- block-wide 2-value sum reduction (256 threads) ------------
__device__ __forceinline__ void block_reduce2(float& a, float& b, float* red) {
#pragma unroll
    for (int m = 32; m > 0; m >>= 1) {
        a += __shfl_xor(a, m, 64);
        b += __shfl_xor(b, m, 64);
    }
    int wid = threadIdx.x >> 6, lane = threadIdx.x & 63;
    __syncthreads();
    if (lane == 0) { red[wid] = a; red[4 + wid] = b; }
    __syncthreads();
    a = red[0] + red[1] + red[2] + red[3];
    b = red[4] + red[5] + red[6] + red[7];
}

// ---------------- x_pos = bf16(x + pos_emb) --------------------------------
__global__ __launch_bounds__(256) void add_pos(const float* __restrict__ x,
                                               const float* __restrict__ pos,
                                               __bf16* __restrict__ xp) {
    const int total4 = (BATCH * SEQL * DIM) / 4;
    const int pos4m = (SEQL * DIM) / 4 - 1;
    for (int i = blockIdx.x * 256 + threadIdx.x; i < total4; i += gridDim.x * 256) {
        f32x4 xv = ((const f32x4*)x)[i];
        f32x4 pv = ((const f32x4*)pos)[i & pos4m];
        bf16x4 o;
#pragma unroll
        for (int j = 0; j < 4; ++j) o[j] = f2bf(xv[j] + pv[j]);
        ((bf16x4*)xp)[i] = o;
    }
}

// ---------------- pooled[b][d] = mean_s x[b,s,d] ---------------------------
__global__ __launch_bounds__(256) void pool_mean(const float* __restrict__ x,
                                                 float* __restrict__ pooled) {
    int b = blockIdx.x >> 2;
    int d = ((blockIdx.x & 3) << 8) + threadIdx.x;
    const float* p = x + (size_t)b * SEQL * DIM + d;
    float s = 0.f;
    for (int ss = 0; ss < SEQL; ++ss) s += p[(size_t)ss * DIM];
    pooled[b * DIM + d] = s * (1.f / SEQL);
}

// ---------------- lat rows 4..67 = latents ---------------------------------
__global__ __launch_bounds__(256) void lat_fill(const float* __restrict__ latents,
                                                float* __restrict__ lat) {
    int i = blockIdx.x * 256 + threadIdx.x;
    int b = i >> 14;
    int rem = i & 16383;
    int r = rem >> 8, d4 = rem & 255;
    ((f32x4*)lat)[(size_t)(b * LTOT + 4 + r) * 256 + d4] = ((const f32x4*)latents)[rem];
}

// ---------------- row LayerNorm -> bf16 (vectorized) ------------------------
template <typename Tin, bool STD, int COLS>
__global__ __launch_bounds__(256) void ln_rows(const Tin* __restrict__ in,
                                               __bf16* __restrict__ out,
                                               const float* __restrict__ w,
                                               const float* __restrict__ bb) {
    __shared__ float red[8];
    constexpr int NPT = COLS / 256;
    size_t base = (size_t)blockIdx.x * COLS;
    int t = threadIdx.x;
    int c0 = t * NPT;
    float xv[NPT];
    float s = 0.f, s2 = 0.f;
#pragma unroll
    for (int k4 = 0; k4 < NPT / 4; ++k4) {
        if constexpr (sizeof(Tin) == 2) {
            bf16x4 v = *(const bf16x4*)(in + base + c0 + k4 * 4);
#pragma unroll
            for (int e = 0; e < 4; ++e) {
                float f = bf2f(v[e]);
                xv[k4 * 4 + e] = f; s += f; s2 += f * f;
            }
        } else {
            f32x4 v = *(const f32x4*)((const float*)in + base + c0 + k4 * 4);
#pragma unroll
            for (int e = 0; e < 4; ++e) {
                float f = v[e];
                xv[k4 * 4 + e] = f; s += f; s2 += f * f;
            }
        }
    }
    block_reduce2(s, s2, red);
    float mean = s * (1.f / COLS);
    float var = s2 * (1.f / COLS) - mean * mean;
    float rstd = rsqrtf(var + LN_EPS);
#pragma unroll
    for (int k4 = 0; k4 < NPT / 4; ++k4) {
        f32x4 wv = *(const f32x4*)(w + c0 + k4 * 4);
        f32x4 bv;
        if (STD) bv = *(const f32x4*)(bb + c0 + k4 * 4);
        bf16x4 o;
#pragma unroll
        for (int e = 0; e < 4; ++e) {
            float y = (xv[k4 * 4 + e] - mean) * rstd * wv[e];
            if (STD) y += bv[e];
            o[e] = f2bf(y);
        }
        *(bf16x4*)(out + base + c0 + k4 * 4) = o;
    }
}

// ------- fused: lat = std_ln(gin)*w+b + lat ; ffin = custom_ln(lat)*g1 -----
__global__ __launch_bounds__(256) void wout_ln_res(const float* __restrict__ gin,
                                                   float* __restrict__ lat,
                                                   __bf16* __restrict__ ffin,
                                                   const float* __restrict__ w,
                                                   const float* __restrict__ b,
                                                   const float* __restrict__ g1) {
    __shared__ float red[8];
    size_t base = (size_t)blockIdx.x * DIM;
    int t = threadIdx.x;
    float xv[4];
    float s = 0.f, s2 = 0.f;
#pragma unroll
    for (int k = 0; k < 4; ++k) {
        float v = gin[base + t + (k << 8)];
        xv[k] = v; s += v; s2 += v * v;
    }
    block_reduce2(s, s2, red);
    float mean = s * (1.f / DIM);
    float var = s2 * (1.f / DIM) - mean * mean;
    float rstd = rsqrtf(var + LN_EPS);
    float yv[4];
    s = 0.f; s2 = 0.f;
#pragma unroll
    for (int k = 0; k < 4; ++k) {
        int c = t + (k << 8);
        float y = (xv[k] - mean) * rstd * w[c] + b[c] + lat[base + c];
        yv[k] = y; s += y; s2 += y * y;
        lat[base + c] = y;
    }
    block_reduce2(s, s2, red);
    float mean2 = s * (1.f / DIM);
    float var2 = s2 * (1.f / DIM) - mean2 * mean2;
    float rstd2 = rsqrtf(var2 + LN_EPS);
#pragma unroll
    for (int k = 0; k < 4; ++k) {
        int c = t + (k << 8);
        ffin[base + c] = f2bf((yv[k] - mean2) * rstd2 * g1[c]);
    }
}

// ---------------- all 5 weight transposes for one layer in one launch ------
// f32 [K,N] -> bf16 [N,K]; ranges hardcoded. 12288 blocks.
__global__ __launch_bounds__(256) void transpose_all(
    const float* __restrict__ Wq, const float* __restrict__ Wkv,
    const float* __restrict__ Wout, const float* __restrict__ f1,
    const float* __restrict__ f2,
    __bf16* __restrict__ wqT, __bf16* __restrict__ wkvT,
    __bf16* __restrict__ woutT, __bf16* __restrict__ f1T,
    __bf16* __restrict__ f2T) {
    __shared__ float tile[32][33];
    int bid = blockIdx.x;
    const float* in; __bf16* out; int N, nxs, ti;
    if (bid < 1024)      { in = Wq;  out = wqT;  N = 1024; nxs = 5; ti = bid; }
    else if (bid < 3072) { in = Wkv; out = wkvT; N = 2048; nxs = 6; ti = bid - 1024; }
    else if (bid < 4096) { in = Wout;out = woutT;N = 1024; nxs = 5; ti = bid - 3072; }
    else if (bid < 8192) { in = f1;  out = f1T;  N = 4096; nxs = 7; ti = bid - 4096; }
    else                 { in = f2;  out = f2T;  N = 1024; nxs = 5; ti = bid - 8192; }
    // K = (bid >= 8192) ? 4096 : 1024
    int K = (bid >= 8192) ? 4096 : 1024;
    int n0 = (ti & ((1 << nxs) - 1)) << 5;
    int k0 = (ti >> nxs) << 5;
    int tx = threadIdx.x & 31, ty = threadIdx.x >> 5;
#pragma unroll
    for (int p = 0; p < 4; ++p) {
        int kk = ty + p * 8;
        tile[kk][tx] = in[(size_t)(k0 + kk) * N + n0 + tx];
    }
    __syncthreads();
#pragma unroll
    for (int p = 0; p < 4; ++p) {
        int nn = ty + p * 8;
        out[(size_t)(n0 + nn) * K + k0 + tx] = f2bf(tile[tx][nn]);
    }
}

// ---------------- transpose + cast: in[K,N] f32 -> out[N,K] bf16 -----------
__global__ __launch_bounds__(256) void transpose_cast(const float* __restrict__ in,
                                                      __bf16* __restrict__ out,
                                                      int K, int N) {
    __shared__ float tile[32][33];
    int n0 = blockIdx.x * 32, k0 = blockIdx.y * 32;
    int tx = threadIdx.x & 31, ty = threadIdx.x >> 5;
#pragma unroll
    for (int p = 0; p < 4; ++p) {
        int kk = ty + p * 8;
        tile[kk][tx] = in[(size_t)(k0 + kk) * N + n0 + tx];
    }
    __syncthreads();
#pragma unroll
    for (int p = 0; p < 4; ++p) {
        int nn = ty + p * 8;
        out[(size_t)(n0 + nn) * K + k0 + tx] = f2bf(tile[tx][nn]);
    }
}

// ---------------- 128x128 MFMA GEMM (m97 structure), pow2 epilogue ---------
// EPI: 0=f32, 1=bf16, 2=bf16*scale, 3=gelu->f32
template <int EPI, bool POW2>
__global__ __launch_bounds__(256) void gemm_bf16(
    const __bf16* __restrict__ A, const __bf16* __restrict__ Bt,
    void* __restrict__ Cout, const float* __restrict__ bias,
    int M, int N, int K, int lda, int ldb, int brs, long long bstride, int ldc,
    float scale, int az, long long cz) {
    __shared__ __bf16 As[128][64];
    __shared__ __bf16 Bs[128][64];
    const int t = threadIdx.x;
    const int m0 = blockIdx.y * 128, n0 = blockIdx.x * 128;
    A += (size_t)blockIdx.z * az;
    Bt += (size_t)blockIdx.z * az;
    const long long zoff = (long long)blockIdx.z * cz;
    const int wid = t >> 6, lane = t & 63;
    const int wr = wid >> 1, wc = wid & 1;
    const int lrow = lane & 15;
    const int lr = lane >> 3, lc = lane & 7;
    const int src_col = (lc ^ lr) << 3;
    f32x4 acc[4][4] = {};

    int garow[4], gbrow[4];
#pragma unroll
    for (int it = 0; it < 4; ++it) {
        int r = wid * 8 + it * 32 + lr;
        int gm = m0 + r; garow[it] = gm < M ? gm : M - 1;
        int gn = n0 + r; gbrow[it] = gn < N ? gn : N - 1;
    }

    for (int kt = 0; kt < K; kt += 64) {
#pragma unroll
        for (int it = 0; it < 4; ++it) {
            int rb = wid * 8 + it * 32;
            gld_lds16(A + (size_t)garow[it] * lda + kt + src_col, &As[rb][0]);
            gld_lds16(Bt + (size_t)gbrow[it] * ldb + kt + src_col, &Bs[rb][0]);
        }
        __syncthreads();
#pragma unroll
        for (int kc = 0; kc < 2; ++kc) {
            const int ck = (kc << 2) + (lane >> 4);
            bf16x8 af[4], bfr[4];
#pragma unroll
            for (int f = 0; f < 4; ++f) {
                int ra = wr * 64 + f * 16 + lrow;
                af[f] = *(const bf16x8*)(&As[ra][(ck ^ (ra & 7)) << 3]);
                int rb = wc * 64 + f * 16 + lrow;
                bfr[f] = *(const bf16x8*)(&Bs[rb][(ck ^ (rb & 7)) << 3]);
            }
#pragma unroll
            for (int fm = 0; fm < 4; ++fm)
#pragma unroll
                for (int fn = 0; fn < 4; ++fn)
                    acc[fm][fn] = __builtin_amdgcn_mfma_f32_16x16x32_bf16(
                        af[fm], bfr[fn], acc[fm][fn], 0, 0, 0);
        }
        __syncthreads();
    }
    const int rbase = (lane >> 4) << 2;
    const int cofs = lane & 15;
    const int msk = POW2 ? (int)((1u << brs) - 1u) : 0;
#pragma unroll
    for (int fm = 0; fm < 4; ++fm) {
#pragma unroll
        for (int j = 0; j < 4; ++j) {
            int m = m0 + wr * 64 + fm * 16 + rbase + j;
            if (m >= M) continue;
            long long roff;
            if (POW2) roff = (long long)(m >> brs) * bstride + (long long)(m & msk) * ldc;
            else      roff = (long long)(m / brs) * bstride + (long long)(m % brs) * ldc;
            roff += zoff;
#pragma unroll
            for (int fn = 0; fn < 4; ++fn) {
                int n = n0 + wc * 64 + fn * 16 + cofs;
                if (n >= N) continue;
                float v = acc[fm][fn][j];
                if (bias) v += bias[n];
                if (EPI == 0) ((float*)Cout)[roff + n] = v;
                else if (EPI == 1) ((__bf16*)Cout)[roff + n] = f2bf(v);
                else if (EPI == 2) ((__bf16*)Cout)[roff + n] = f2bf(v * scale);
                else ((float*)Cout)[roff + n] =
                    0.5f * v * (1.0f + erff(v * 0.70710678118654752f));
            }
        }
    }
}

// ---------------- 256x256 8-phase counted-vmcnt GEMM (m201 port) -----------
// Used for the kv projection only (M=16384, 512 blocks = 2 clean rounds).
template <int EPI>
__global__ __launch_bounds__(512, 2) void gemm256(
    const __bf16* __restrict__ A, const __bf16* __restrict__ Bt,
    void* __restrict__ Cout, const float* __restrict__ bias,
    int M, int N, int K, int brs, long long bstride, int ldc, float scale,
    int gxs) {
    __shared__ __bf16 As[2][256][64];
    __shared__ __bf16 Bs[2][256][64];
    const int t = threadIdx.x;
    const int wid = t >> 6, lane = t & 63;
    const int wr = wid >> 2, wc = wid & 3;
    const int lrow = lane & 15, lk = lane >> 4;
    const int lr8 = lane >> 3;
    const int scol = ((lane & 7) ^ lr8) << 3;

    int nwg = gridDim.x;
    int L = blockIdx.x;
    if ((nwg & 7) == 0) L = (L & 7) * (nwg >> 3) + (L >> 3);
    const int bx = L & ((1 << gxs) - 1), by = L >> gxs;
    const int m0 = by * 256, n0 = bx * 256;

    unsigned aoff[4], boff[4];
#pragma unroll
    for (int h = 0; h < 2; ++h)
#pragma unroll
        for (int rnd = 0; rnd < 2; ++rnd) {
            int r = h * 128 + rnd * 64 + wid * 8 + lr8;
            int gm = m0 + r; if (gm > M - 1) gm = M - 1;
            aoff[h * 2 + rnd] = (unsigned)(gm * K + scol);
            int gn = n0 + r; if (gn > N - 1) gn = N - 1;
            boff[h * 2 + rnd] = (unsigned)(gn * K + scol);
        }

    auto stgA = [&](int buf, int tile, int h) {
        int kt = tile << 6;
        gld_lds16(A + aoff[h * 2 + 0] + kt, &As[buf][h * 128 + wid * 8][0]);
        gld_lds16(A + aoff[h * 2 + 1] + kt, &As[buf][h * 128 + 64 + wid * 8][0]);
    };
    auto stgB = [&](int buf, int tile, int h) {
        int kt = tile << 6;
        gld_lds16(Bt + boff[h * 2 + 0] + kt, &Bs[buf][h * 128 + wid * 8][0]);
        gld_lds16(Bt + boff[h * 2 + 1] + kt, &Bs[buf][h * 128 + 64 + wid * 8][0]);
    };

    f32x4 acc[8][4] = {};
    bf16x8 AF0[4][2], AF1[4][2], BF[2][2], BF2[2][2];

    auto rdAF = [&](bf16x8 (&AF)[4][2], int buf, int qm) {
#pragma unroll
        for (int i = 0; i < 4; ++i) {
            int ra = wr * 128 + (qm * 4 + i) * 16 + lrow;
            AF[i][0] = *(const bf16x8*)(&As[buf][ra][((lk) ^ (ra & 7)) << 3]);
            AF[i][1] = *(const bf16x8*)(&As[buf][ra][((4 + lk) ^ (ra & 7)) << 3]);
        }
    };
    auto rdBF = [&](bf16x8 (&BV)[2][2], int buf, int qn) {
#pragma unroll
        for (int i = 0; i < 2; ++i) {
            int rb = wc * 64 + (qn * 2 + i) * 16 + lrow;
            BV[i][0] = *(const bf16x8*)(&Bs[buf][rb][((lk) ^ (rb & 7)) << 3]);
            BV[i][1] = *(const bf16x8*)(&Bs[buf][rb][((4 + lk) ^ (rb & 7)) << 3]);
        }
    };
    auto mfq = [&](bf16x8 (&AF)[4][2], bf16x8 (&BV)[2][2], int mo, int no) {
        __builtin_amdgcn_s_setprio(1);
#pragma unroll
        for (int i = 0; i < 4; ++i)
#pragma unroll
            for (int nf = 0; nf < 2; ++nf)
#pragma unroll
                for (int ks = 0; ks < 2; ++ks)
                    acc[mo + i][no + nf] = __builtin_amdgcn_mfma_f32_16x16x32_bf16(
                        AF[i][ks], BV[nf][ks], acc[mo + i][no + nf], 0, 0, 0);
        __builtin_amdgcn_s_setprio(0);
    };

    const int nt = K >> 6;
    stgA(0, 0, 0); stgA(0, 0, 1);
    stgB(0, 0, 0); stgB(0, 0, 1);
    stgA(1, 1, 0); stgA(1, 1, 1);
    VMCNT4();
    SBAR();

    for (int tt = 0; tt < nt; tt += 2) {
        const int t1 = tt + 1;
        const int t2 = (tt + 2 < nt) ? tt + 2 : nt - 1;
        const int t3 = (tt + 3 < nt) ? tt + 3 : nt - 1;
        // P1
        rdAF(AF0, 0, 0); rdBF(BF, 0, 0);
        stgB(1, t1, 0);
        SBAR();
        mfq(AF0, BF, 0, 0);
        SBAR();
        // P2
        rdAF(AF1, 0, 1);
        stgB(1, t1, 1);
        SBAR();
        mfq(AF1, BF, 4, 0);
        SBAR();
        // P3
        rdBF(BF2, 0, 1);
        stgA(0, t2, 0);
        SBAR();
        mfq(AF1, BF2, 4, 2);
        SBAR();
        // P4
        stgA(0, t2, 1);
        SBAR();
        mfq(AF0, BF2, 0, 2);
        VMCNT4();
        SBAR();
        // P5
        rdAF(AF0, 1, 0); rdBF(BF, 1, 0);
        stgB(0, t2, 0);
        SBAR();
        mfq(AF0, BF, 0, 0);
        SBAR();
        // P6
        rdAF(AF1, 1, 1);
        stgB(0, t2, 1);
        SBAR();
        mfq(AF1, BF, 4, 0);
        SBAR();
        // P7
        rdBF(BF2, 1, 1);
        stgA(1, t3, 0);
        SBAR();
        mfq(AF1, BF2, 4, 2);
        SBAR();
        // P8
        stgA(1, t3, 1);
        SBAR();
        mfq(AF0, BF2, 0, 2);
        VMCNT4();
        SBAR();
    }

    const int rbase = (lane >> 4) << 2;
    const int cofs = lane & 15;
    const int msk = (int)((1u << brs) - 1u);
#pragma unroll
    for (int mf = 0; mf < 8; ++mf) {
#pragma unroll
        for (int j = 0; j < 4; ++j) {
            int m = m0 + wr * 128 + mf * 16 + rbase + j;
            if (m >= M) continue;
            long long roff = (long long)(m >> brs) * bstride +
                             (long long)(m & msk) * ldc;
#pragma unroll
            for (int nf = 0; nf < 4; ++nf) {
                int n = n0 + wc * 64 + nf * 16 + cofs;
                if (n >= N) continue;
                float v = acc[mf][nf][j];
                if (bias) v += bias[n];
                if (EPI == 1) ((__bf16*)Cout)[roff + n] = f2bf(v);
                else if (EPI == 3) ((float*)Cout)[roff + n] =
                    0.5f * v * (1.0f + erff(v * 0.70710678118654752f));
                else ((float*)Cout)[roff + n] = v;
            }
        }
    }
}

// ---------------- split-K reduce: lat += p0+p1+p2+p3 -----------------------
__global__ __launch_bounds__(256) void splitk_add(const float* __restrict__ p,
                                                  float* __restrict__ lat) {
    const int S = (2176 * 1024) / 4;
    int i = blockIdx.x * 256 + threadIdx.x;
    f32x4 a = ((const f32x4*)p)[i];
    f32x4 b = ((const f32x4*)p)[i + S];
    f32x4 c = ((const f32x4*)p)[i + 2 * S];
    f32x4 d = ((const f32x4*)p)[i + 3 * S];
    f32x4 l = ((f32x4*)lat)[i];
    l = l + a + b + c + d;
    ((f32x4*)lat)[i] = l;
}

// ---------------- attention: S = Q @ K^T (MFMA) ----------------------------
__global__ __launch_bounds__(256) void qk_gemm(const __bf16* __restrict__ q,
                                               const __bf16* __restrict__ kv,
                                               __bf16* __restrict__ sp) {
    __shared__ __bf16 Qs[80][64];
    __shared__ __bf16 Ks[128][64];
    const int bh = blockIdx.x, b = bh >> 4, h = bh & 15;
    const int n0 = blockIdx.y * 128;
    const int t = threadIdx.x, wid = t >> 6, lane = t & 63;
    const __bf16* qbase = q + (size_t)b * LTOT * DIM + h * DH;
    const __bf16* kbase = kv + (size_t)b * KEYS * 2048 + h * DH;
    const bf16x8 zero8 = {};

    for (int s = t; s < 80 * 8; s += 256) {
        int r = s >> 3, c8 = s & 7;
        bf16x8 v = zero8;
        if (r < LTOT) v = *(const bf16x8*)(qbase + (size_t)r * DIM + (c8 << 3));
        *(bf16x8*)(&Qs[r][(c8 ^ (r & 7)) << 3]) = v;
    }
    for (int s = t; s < 128 * 8; s += 256) {
        int r = s >> 3, c8 = s & 7;
        int gk = n0 + r; if (gk >= KEYS) gk = KEYS - 1;
        bf16x8 v = *(const bf16x8*)(kbase + (size_t)gk * 2048 + (c8 << 3));
        *(bf16x8*)(&Ks[r][(c8 ^ (r & 7)) << 3]) = v;
    }
    __syncthreads();

    const int lrow = lane & 15;
    f32x4 acc[5][2] = {};
#pragma unroll
    for (int kc = 0; kc < 2; ++kc) {
        const int ck = (kc << 2) + (lane >> 4);
        bf16x8 bfr[2];
#pragma unroll
        for (int fn = 0; fn < 2; ++fn) {
            int rb = wid * 32 + fn * 16 + lrow;
            bfr[fn] = *(const bf16x8*)(&Ks[rb][(ck ^ (rb & 7)) << 3]);
        }
#pragma unroll
        for (int fm = 0; fm < 5; ++fm) {
            int ra = fm * 16 + lrow;
            bf16x8 af = *(const bf16x8*)(&Qs[ra][(ck ^ (ra & 7)) << 3]);
#pragma unroll
            for (int fn = 0; fn < 2; ++fn)
                acc[fm][fn] = __builtin_amdgcn_mfma_f32_16x16x32_bf16(
                    af, bfr[fn], acc[fm][fn], 0, 0, 0);
        }
    }
    __bf16* srow = sp + (size_t)bh * LTOT * KPAD;
    const int rbase = (lane >> 4) << 2, cofs = lane & 15;
#pragma unroll
    for (int fm = 0; fm < 5; ++fm)
#pragma unroll
        for (int j = 0; j < 4; ++j) {
            int r = fm * 16 + rbase + j;
            if (r >= LTOT) continue;
#pragma unroll
            for (int fn = 0; fn < 2; ++fn) {
                int col = n0 + wid * 32 + fn * 16 + cofs;
                srow[(size_t)r * KPAD + col] = f2bf(acc[fm][fn][j]);
            }
        }
}

// ---------------- row softmax in place, writes P/l, zeros for pad ----------
__global__ __launch_bounds__(256) void softmax_p(__bf16* __restrict__ sp) {
    const int row = blockIdx.x * 4 + (threadIdx.x >> 6);
    const int lane = threadIdx.x & 63;
    __bf16* p = sp + (size_t)row * KPAD;
    float v[10];
    float m = -3.0e38f;
#pragma unroll
    for (int i = 0; i < 10; ++i) {
        int c = (i << 6) + lane;
        float f = (c < KEYS) ? bf2f(p[c]) : -3.0e38f;
        v[i] = f; m = fmaxf(m, f);
    }
#pragma unroll
    for (int mk = 32; mk > 0; mk >>= 1) m = fmaxf(m, __shfl_xor(m, mk, 64));
    float l = 0.f;
#pragma unroll
    for (int i = 0; i < 10; ++i) {
        int c = (i << 6) + lane;
        float e = (c < KEYS) ? __expf(v[i] - m) : 0.f;
        v[i] = e; l += e;
    }
#pragma unroll
    for (int mk = 32; mk > 0; mk >>= 1) l += __shfl_xor(l, mk, 64);
    float inv = 1.f / l;
#pragma unroll
    for (int i = 0; i < 10; ++i) {
        int c = (i << 6) + lane;
        p[c] = f2bf(v[i] * inv);
    }
}

// ---------------- vt[bh][d][k] = v[b][k][h*64+d] ---------------------------
__global__ __launch_bounds__(256) void vt_tr(const __bf16* __restrict__ kv,
                                             __bf16* __restrict__ vt) {
    __shared__ __bf16 tile[32][34];
    const int bh = blockIdx.x, b = bh >> 4, h = bh & 15;
    const int k0 = blockIdx.y * 32, d0 = blockIdx.z * 32;
    const int tx = threadIdx.x & 31, ty = threadIdx.x >> 5;
    const __bf16* vbase = kv + (size_t)b * KEYS * 2048 + 1024 + h * DH;
#pragma unroll
    for (int p = 0; p < 4; ++p) {
        int kk = k0 + ty + p * 8;
        int kc = kk < KEYS ? kk : KEYS - 1;
        tile[ty + p * 8][tx] = vbase[(size_t)kc * 2048 + d0 + tx];
    }
    __syncthreads();
    __bf16* obase = vt + (size_t)bh * DH * KPAD;
#pragma unroll
    for (int p = 0; p < 4; ++p) {
        int nn = ty + p * 8;
        __bf16 val = (k0 + tx < KEYS) ? tile[tx][nn] : (__bf16)0.f;
        obase[(size_t)(d0 + nn) * KPAD + k0 + tx] = val;
    }
}

// ---------------- O = P @ V (MFMA), grid 512 bh ----------------------------
__global__ __launch_bounds__(256) void pv_gemm(const __bf16* __restrict__ sp,
                                               const __bf16* __restrict__ vt,
                                               __bf16* __restrict__ ao) {
    __shared__ __bf16 Ps[80][64];
    __shared__ __bf16 Vs[64][64];
    const int bh = blockIdx.x, b = bh >> 4, h = bh & 15;
    const int t = threadIdx.x, wid = t >> 6, lane = t & 63;
    const int lrow = lane & 15;
    const __bf16* pbase = sp + (size_t)bh * LTOT * KPAD;
    const __bf16* vbase = vt + (size_t)bh * DH * KPAD;
    const bf16x8 zero8 = {};
    f32x4 acc[5] = {};

    for (int kt = 0; kt < KPAD; kt += 64) {
        for (int s = t; s < 80 * 8; s += 256) {
            int r = s >> 3, c8 = s & 7;
            bf16x8 v = zero8;
            if (r < LTOT) v = *(const bf16x8*)(pbase + (size_t)r * KPAD + kt + (c8 << 3));
            *(bf16x8*)(&Ps[r][(c8 ^ (r & 7)) << 3]) = v;
        }
        for (int s = t; s < 64 * 8; s += 256) {
            int r = s >> 3, c8 = s & 7;
            bf16x8 v = *(const bf16x8*)(vbase + (size_t)r * KPAD + kt + (c8 << 3));
            *(bf16x8*)(&Vs[r][(c8 ^ (r & 7)) << 3]) = v;
        }
        __syncthreads();
#pragma unroll
        for (int kc = 0; kc < 2; ++kc) {
            const int ck = (kc << 2) + (lane >> 4);
            int rb = wid * 16 + lrow;
            bf16x8 bfr = *(const bf16x8*)(&Vs[rb][(ck ^ (rb & 7)) << 3]);
#pragma unroll
            for (int fm = 0; fm < 5; ++fm) {
                int ra = fm * 16 + lrow;
                bf16x8 af = *(const bf16x8*)(&Ps[ra][(ck ^ (ra & 7)) << 3]);
                acc[fm] = __builtin_amdgcn_mfma_f32_16x16x32_bf16(
                    af, bfr, acc[fm], 0, 0, 0);
            }
        }
        __syncthreads();
    }
    __bf16* obase = ao + (size_t)b * LTOT * DIM + h * DH;
    const int rbase = (lane >> 4) << 2, cofs = lane & 15;
#pragma unroll
    for (int fm = 0; fm < 5; ++fm)
#pragma unroll
        for (int j = 0; j < 4; ++j) {
            int r = fm * 16 + rbase + j;
            if (r >= LTOT) continue;
            obase[(size_t)r * DIM + wid * 16 + cofs] = f2bf(acc[fm][j]);
        }
}

// ---------------------------------------------------------------------------
template <int EPI, bool POW2>
static void g128(const __bf16* A, const __bf16* Bt, void* C, const float* bias,
                 int M, int N, int K, int lda, int ldb, int brs, long long bs,
                 int ldc, float scale, int gz, int az, long long cz,
                 hipStream_t s) {
    dim3 g(N / 128, (M + 127) / 128, gz);
    gemm_bf16<EPI, POW2><<<g, 256, 0, s>>>(A, Bt, C, bias, M, N, K, lda, ldb,
                                           brs, bs, ldc, scale, az, cz);
}

extern "C" void kernel_launch(void* const* d_in, const int* in_sizes, int n_in,
                              void* d_out, int out_size, void* d_ws, size_t ws_size,
                              hipStream_t stream) {
    (void)in_sizes; (void)n_in; (void)out_size; (void)ws_size;
    const float* x          = (const float*)d_in[0];
    const float* pos_emb    = (const float*)d_in[2];
    const float* latents    = (const float*)d_in[3];
    const float* mp_ln_g    = (const float*)d_in[4];
    const float* mp_w       = (const float*)d_in[5];
    const float* mp_b       = (const float*)d_in[6];
    const float* attn_norm_w= (const float*)d_in[7];
    const float* attn_norm_b= (const float*)d_in[8];
    const float* attn_lat_w = (const float*)d_in[9];
    const float* attn_lat_b = (const float*)d_in[10];
    const float* Wq         = (const float*)d_in[11];
    const float* Wkv        = (const float*)d_in[12];
    const float* Wout       = (const float*)d_in[13];
    const float* out_ln_w   = (const float*)d_in[14];
    const float* out_ln_b   = (const float*)d_in[15];
    const float* ff_ln1_g   = (const float*)d_in[16];
    const float* ff_w1      = (const float*)d_in[17];
    const float* ff_ln2_g   = (const float*)d_in[18];
    const float* ff_w2      = (const float*)d_in[19];

    float* lat = (float*)d_out;                    // residual stream, f32

    char* ws = (char*)d_ws;
    size_t off = 0;
    auto take = [&](size_t bytes) -> char* {
        char* p = ws + off;
        off += (bytes + 255) & ~(size_t)255;
        return p;
    };
    __bf16* xpos = (__bf16*)take(2ULL * BATCH * SEQL * DIM);
    __bf16* xn   = (__bf16*)take(2ULL * BATCH * SEQL * DIM);
    __bf16* lnl  = (__bf16*)take(2ULL * BATCH * LTOT * DIM);
    __bf16* ffin = (__bf16*)take(2ULL * BATCH * LTOT * DIM);
    __bf16* qb   = (__bf16*)take(2ULL * BATCH * LTOT * DIM);
    __bf16* ao   = (__bf16*)take(2ULL * BATCH * LTOT * DIM);
    __bf16* kvb  = (__bf16*)take(2ULL * BATCH * KEYS * 2048);
    float*  gout = (float*)take(4ULL * BATCH * LTOT * HID);   // sp / ff2-partials overlay
    __bf16* h2   = (__bf16*)take(2ULL * BATCH * LTOT * HID);  // sp spills here
    __bf16* vt   = (__bf16*)take(2ULL * BATCH * HEADS * DH * KPAD);
    __bf16* wT   = (__bf16*)take(2ULL * 12 * 1024 * 1024);
    float*  pooled = (float*)take(4ULL * BATCH * DIM);
    __bf16* mpin = (__bf16*)take(2ULL * BATCH * DIM);

    __bf16* sp = (__bf16*)gout;            // 44.6 MB, disjoint lifetime

    __bf16* wqT   = wT;                    // [1024,1024]
    __bf16* wkvT  = wT + 1 * 1024 * 1024;  // [2048,1024]
    __bf16* woutT = wT + 3 * 1024 * 1024;  // [1024,1024]
    __bf16* f1T   = wT + 4 * 1024 * 1024;  // [4096,1024]
    __bf16* f2T   = wT + 8 * 1024 * 1024;  // [1024,4096]
    __bf16* mpwT  = wT;                    // [4096,1024], used before layers

    // ---- prologue -----------------------------------------------------
    add_pos<<<4096, 256, 0, stream>>>(x, pos_emb, xpos);
    pool_mean<<<128, 256, 0, stream>>>(x, pooled);
    ln_rows<float, false, DIM><<<BATCH, 256, 0, stream>>>(pooled, mpin, mp_ln_g, nullptr);
    transpose_cast<<<dim3(128, 32), 256, 0, stream>>>(mp_w, mpwT, 1024, 4096);
    g128<0, true>(mpin, mpwT, lat, mp_b, BATCH, 4096, 1024, 1024, 1024,
                  5, 0, LTOT * DIM, 1.f, 1, 0, 0, stream);
    lat_fill<<<2048, 256, 0, stream>>>(latents, lat);

    // ---- layers -------------------------------------------------------
    for (int i = 0; i < 4; ++i) {
        transpose_all<<<12288, 256, 0, stream>>>(
            Wq + (size_t)i * 1024 * 1024, Wkv + (size_t)i * 1024 * 2048,
            Wout + (size_t)i * 1024 * 1024, ff_w1 + (size_t)i * 1024 * 4096,
            ff_w2 + (size_t)i * 4096 * 1024,
            wqT, wkvT, woutT, f1T, f2T);

        ln_rows<__bf16, true, DIM><<<BATCH * SEQL, 256, 0, stream>>>(
            xpos, xn, attn_norm_w + i * DIM, attn_norm_b + i * DIM);
        ln_rows<float, true, DIM><<<BATCH * LTOT, 256, 0, stream>>>(
            lat, lnl, attn_lat_w + i * DIM, attn_lat_b + i * DIM);

        // q = (lnl @ Wq) * 0.125 -> bf16
        g128<2, true>(lnl, wqT, qb, nullptr, BATCH * LTOT, 1024, 1024, 1024, 1024,
                      31, 0, 1024, 0.125f, 1, 0, 0, stream);
        // kv rows 0..511 per batch from xn (256x256 8-phase kernel)
        gemm256<1><<<dim3(512), 512, 0, stream>>>(
            xn, wkvT, kvb, nullptr, BATCH * SEQL, 2048, 1024,
            9, (long long)KEYS * 2048, 2048, 1.f, 3);
        // kv rows 512..579 per batch from lnl
        g128<1, false>(lnl, wkvT, kvb + 512 * 2048, nullptr, BATCH * LTOT, 2048, 1024,
                       1024, 1024, LTOT, (long long)KEYS * 2048, 2048, 1.f, 1, 0, 0, stream);

        // ---- MFMA attention ----
        vt_tr<<<dim3(BATCH * HEADS, KPAD / 32, 2), 256, 0, stream>>>(kvb, vt);
        qk_gemm<<<dim3(BATCH * HEADS, KPAD / 128), 256, 0, stream>>>(qb, kvb, sp);
        softmax_p<<<(BATCH * HEADS * LTOT) / 4, 256, 0, stream>>>(sp);
        pv_gemm<<<BATCH * HEADS, 256, 0, stream>>>(sp, vt, ao);

        g128<0, true>(ao, woutT, gout, nullptr, BATCH * LTOT, 1024, 1024, 1024, 1024,
                      31, 0, 1024, 1.f, 1, 0, 0, stream);
        wout_ln_res<<<BATCH * LTOT, 256, 0, stream>>>(
            gout, lat, ffin, out_ln_w + i * DIM, out_ln_b + i * DIM, ff_ln1_g + i * DIM);

        // ff1 (gelu) back on the 128x128 kernel (544 blocks, good fill)
        g128<3, true>(ffin, f1T, gout, nullptr, BATCH * LTOT, HID, 1024, 1024, 1024,
                      31, 0, HID, 1.f, 1, 0, 0, stream);
        ln_rows<float, false, HID><<<BATCH * LTOT, 256, 0, stream>>>(
            gout, h2, ff_ln2_g + i * HID, nullptr);
        // ff2 split-K x4 -> partials in gout, then reduce into lat
        g128<0, true>(h2, f2T, gout, nullptr, BATCH * LTOT, 1024, 1024, HID, HID,
                      31, 0, 1024, 1.f, 4, 1024, 2176LL * 1024, stream);
        splitk_add<<<2176, 256, 0, stream>>>(gout, lat);
    }
}

// Round 6
// 1761.502 us; speedup vs baseline: 1.3030x; 1.3030x over previous
//
#include <hip/hip_runtime.h>

// ---------------------------------------------------------------------------
// PerceiverResampler forward, MI355X gfx950.
// R6: all latent-side GEMMs (M=2176) were latency-bound (<=2 blocks/CU).
//     Split-K everywhere: q+kv-tail merged (N=3072, splitK2, 816 blocks),
//     wout splitK4 (544), ff1 splitK2 (1088), ff2 splitK8 (1088).
//     Reduces fused into existing pointwise kernels where possible.
// Residual stream (lat) lives in d_out (f32). Workspace ~261 MB.
// ---------------------------------------------------------------------------

typedef __attribute__((ext_vector_type(4))) float f32x4;
typedef __attribute__((ext_vector_type(8))) __bf16 bf16x8;
typedef __attribute__((ext_vector_type(4))) __bf16 bf16x4;

#define BATCH 32
#define SEQL  512
#define DIM   1024
#define HEADS 16
#define DH    64
#define LTOT  68          // 4 mean-pool latents + 64 learned
#define KEYS  580         // SEQL + LTOT
#define KPAD  640         // KEYS padded to 5*128
#define HID   4096
#define LN_EPS 1e-5f
#define MLAT  2176        // BATCH * LTOT

__device__ __forceinline__ float bf2f(__bf16 v) { return (float)v; }
__device__ __forceinline__ __bf16 f2bf(float v) { return (__bf16)v; }
__device__ __forceinline__ float gelu_f(float v) {
    return 0.5f * v * (1.0f + erff(v * 0.70710678118654752f));
}

// async 16B global -> LDS (wave-uniform LDS base + lane*16)
__device__ __forceinline__ void gld_lds16(const __bf16* g, __bf16* l) {
    __builtin_amdgcn_global_load_lds(
        (const __attribute__((address_space(1))) void*)g,
        (__attribute__((address_space(3))) void*)l, 16, 0, 0);
}

#define SBAR()   asm volatile("s_barrier" ::: "memory")
#define VMCNT4() asm volatile("s_waitcnt vmcnt(4)" ::: "memory")

// ---------------- block-wide 2-value sum reduction (256 threads) ------------
__device__ __forceinline__ void block_reduce2(float& a, float& b, float* red) {
#pragma unroll
    for (int m = 32; m > 0; m >>= 1) {
        a += __shfl_xor(a, m, 64);
        b += __shfl_xor(b, m, 64);
    }
    int wid = threadIdx.x >> 6, lane = threadIdx.x & 63;
    __syncthreads();
    if (lane == 0) { red[wid] = a; red[4 + wid] = b; }
    __syncthreads();
    a = red[0] + red[1] + red[2] + red[3];
    b = red[4] + red[5] + red[6] + red[7];
}

// ---------------- x_pos = bf16(x + pos_emb) --------------------------------
__global__ __launch_bounds__(256) void add_pos(const float* __restrict__ x,
                                               const float* __restrict__ pos,
                                               __bf16* __restrict__ xp) {
    const int total4 = (BATCH * SEQL * DIM) / 4;
    const int pos4m = (SEQL * DIM) / 4 - 1;
    for (int i = blockIdx.x * 256 + threadIdx.x; i < total4; i += gridDim.x * 256) {
        f32x4 xv = ((const f32x4*)x)[i];
        f32x4 pv = ((const f32x4*)pos)[i & pos4m];
        bf16x4 o;
#pragma unroll
        for (int j = 0; j < 4; ++j) o[j] = f2bf(xv[j] + pv[j]);
        ((bf16x4*)xp)[i] = o;
    }
}

// ---------------- pooled[b][d] = mean_s x[b,s,d] ---------------------------
__global__ __launch_bounds__(256) void pool_mean(const float* __restrict__ x,
                                                 float* __restrict__ pooled) {
    int b = blockIdx.x >> 2;
    int d = ((blockIdx.x & 3) << 8) + threadIdx.x;
    const float* p = x + (size_t)b * SEQL * DIM + d;
    float s = 0.f;
    for (int ss = 0; ss < SEQL; ++ss) s += p[(size_t)ss * DIM];
    pooled[b * DIM + d] = s * (1.f / SEQL);
}

// ---------------- lat rows 4..67 = latents ---------------------------------
__global__ __launch_bounds__(256) void lat_fill(const float* __restrict__ latents,
                                                float* __restrict__ lat) {
    int i = blockIdx.x * 256 + threadIdx.x;
    int b = i >> 14;
    int rem = i & 16383;
    int r = rem >> 8, d4 = rem & 255;
    ((f32x4*)lat)[(size_t)(b * LTOT + 4 + r) * 256 + d4] = ((const f32x4*)latents)[rem];
}

// ---------------- row LayerNorm -> bf16 (vectorized) ------------------------
template <typename Tin, bool STD, int COLS>
__global__ __launch_bounds__(256) void ln_rows(const Tin* __restrict__ in,
                                               __bf16* __restrict__ out,
                                               const float* __restrict__ w,
                                               const float* __restrict__ bb) {
    __shared__ float red[8];
    constexpr int NPT = COLS / 256;
    size_t base = (size_t)blockIdx.x * COLS;
    int t = threadIdx.x;
    int c0 = t * NPT;
    float xv[NPT];
    float s = 0.f, s2 = 0.f;
#pragma unroll
    for (int k4 = 0; k4 < NPT / 4; ++k4) {
        if constexpr (sizeof(Tin) == 2) {
            bf16x4 v = *(const bf16x4*)(in + base + c0 + k4 * 4);
#pragma unroll
            for (int e = 0; e < 4; ++e) {
                float f = bf2f(v[e]);
                xv[k4 * 4 + e] = f; s += f; s2 += f * f;
            }
        } else {
            f32x4 v = *(const f32x4*)((const float*)in + base + c0 + k4 * 4);
#pragma unroll
            for (int e = 0; e < 4; ++e) {
                float f = v[e];
                xv[k4 * 4 + e] = f; s += f; s2 += f * f;
            }
        }
    }
    block_reduce2(s, s2, red);
    float mean = s * (1.f / COLS);
    float var = s2 * (1.f / COLS) - mean * mean;
    float rstd = rsqrtf(var + LN_EPS);
#pragma unroll
    for (int k4 = 0; k4 < NPT / 4; ++k4) {
        f32x4 wv = *(const f32x4*)(w + c0 + k4 * 4);
        f32x4 bv;
        if (STD) bv = *(const f32x4*)(bb + c0 + k4 * 4);
        bf16x4 o;
#pragma unroll
        for (int e = 0; e < 4; ++e) {
            float y = (xv[k4 * 4 + e] - mean) * rstd * wv[e];
            if (STD) y += bv[e];
            o[e] = f2bf(y);
        }
        *(bf16x4*)(out + base + c0 + k4 * 4) = o;
    }
}

// ----- ff1 reduce + gelu + custom LN (HID cols): h2 = ln(gelu(a+b))*g ------
__global__ __launch_bounds__(256) void ln_gelu2(const float* __restrict__ a,
                                                const float* __restrict__ b,
                                                __bf16* __restrict__ out,
                                                const float* __restrict__ g) {
    __shared__ float red[8];
    constexpr int NPT = HID / 256;   // 16
    size_t base = (size_t)blockIdx.x * HID;
    int t = threadIdx.x;
    int c0 = t * NPT;
    float xv[NPT];
    float s = 0.f, s2 = 0.f;
#pragma unroll
    for (int k4 = 0; k4 < NPT / 4; ++k4) {
        f32x4 va = *(const f32x4*)(a + base + c0 + k4 * 4);
        f32x4 vb = *(const f32x4*)(b + base + c0 + k4 * 4);
#pragma unroll
        for (int e = 0; e < 4; ++e) {
            float f = gelu_f(va[e] + vb[e]);
            xv[k4 * 4 + e] = f; s += f; s2 += f * f;
        }
    }
    block_reduce2(s, s2, red);
    float mean = s * (1.f / HID);
    float var = s2 * (1.f / HID) - mean * mean;
    float rstd = rsqrtf(var + LN_EPS);
#pragma unroll
    for (int k4 = 0; k4 < NPT / 4; ++k4) {
        f32x4 gv = *(const f32x4*)(g + c0 + k4 * 4);
        bf16x4 o;
#pragma unroll
        for (int e = 0; e < 4; ++e)
            o[e] = f2bf((xv[k4 * 4 + e] - mean) * rstd * gv[e]);
        *(bf16x4*)(out + base + c0 + k4 * 4) = o;
    }
}

// -- fused: wout 4-slab reduce; lat = std_ln(sum)*w+b + lat; ffin = c_ln*g1 --
__global__ __launch_bounds__(256) void wout_ln_res(const float* __restrict__ gin,
                                                   float* __restrict__ lat,
                                                   __bf16* __restrict__ ffin,
                                                   const float* __restrict__ w,
                                                   const float* __restrict__ b,
                                                   const float* __restrict__ g1) {
    __shared__ float red[8];
    const int SL = MLAT * DIM;
    size_t base = (size_t)blockIdx.x * DIM;
    int t = threadIdx.x;
    float xv[4];
    float s = 0.f, s2 = 0.f;
#pragma unroll
    for (int k = 0; k < 4; ++k) {
        size_t idx = base + t + (k << 8);
        float v = gin[idx] + gin[idx + SL] + gin[idx + 2 * SL] + gin[idx + 3 * SL];
        xv[k] = v; s += v; s2 += v * v;
    }
    block_reduce2(s, s2, red);
    float mean = s * (1.f / DIM);
    float var = s2 * (1.f / DIM) - mean * mean;
    float rstd = rsqrtf(var + LN_EPS);
    float yv[4];
    s = 0.f; s2 = 0.f;
#pragma unroll
    for (int k = 0; k < 4; ++k) {
        int c = t + (k << 8);
        float y = (xv[k] - mean) * rstd * w[c] + b[c] + lat[base + c];
        yv[k] = y; s += y; s2 += y * y;
        lat[base + c] = y;
    }
    block_reduce2(s, s2, red);
    float mean2 = s * (1.f / DIM);
    float var2 = s2 * (1.f / DIM) - mean2 * mean2;
    float rstd2 = rsqrtf(var2 + LN_EPS);
#pragma unroll
    for (int k = 0; k < 4; ++k) {
        int c = t + (k << 8);
        ffin[base + c] = f2bf((yv[k] - mean2) * rstd2 * g1[c]);
    }
}

// ---------------- qkv reduce: 2 slabs -> qb (n<1024, *0.125) / kvb tail ----
__global__ __launch_bounds__(256) void qkv_red(const float* __restrict__ pk,
                                               __bf16* __restrict__ qb,
                                               __bf16* __restrict__ kvb) {
    const int S = MLAT * 3072;
    int row = blockIdx.y;
    int n = (blockIdx.x * 256 + threadIdx.x) * 4;
    size_t idx = (size_t)row * 3072 + n;
    f32x4 a = *(const f32x4*)(pk + idx);
    f32x4 b = *(const f32x4*)(pk + S + idx);
    bf16x4 o;
    if (n < 1024) {
#pragma unroll
        for (int e = 0; e < 4; ++e) o[e] = f2bf((a[e] + b[e]) * 0.125f);
        *(bf16x4*)(qb + (size_t)row * 1024 + n) = o;
    } else {
#pragma unroll
        for (int e = 0; e < 4; ++e) o[e] = f2bf(a[e] + b[e]);
        int bb = ((row >> 2) * 61681) >> 20;       // row / 68
        int r = row - bb * 68;
        *(bf16x4*)(kvb + (size_t)bb * KEYS * 2048 + (size_t)(512 + r) * 2048 +
                   (n - 1024)) = o;
    }
}

// ---------------- ff2 reduce: lat += sum of 8 slabs ------------------------
__global__ __launch_bounds__(256) void splitk_add8(const float* __restrict__ p0,
                                                   const float* __restrict__ p1,
                                                   float* __restrict__ lat) {
    const int S = (MLAT * 1024) / 4;
    int i = blockIdx.x * 256 + threadIdx.x;
    f32x4 acc = ((f32x4*)lat)[i];
#pragma unroll
    for (int s = 0; s < 4; ++s) acc += ((const f32x4*)p0)[i + s * S];
#pragma unroll
    for (int s = 0; s < 4; ++s) acc += ((const f32x4*)p1)[i + s * S];
    ((f32x4*)lat)[i] = acc;
}

// ---------------- all 5 weight transposes for one layer in one launch ------
__global__ __launch_bounds__(256) void transpose_all(
    const float* __restrict__ Wq, const float* __restrict__ Wkv,
    const float* __restrict__ Wout, const float* __restrict__ f1,
    const float* __restrict__ f2,
    __bf16* __restrict__ wqT, __bf16* __restrict__ wkvT,
    __bf16* __restrict__ woutT, __bf16* __restrict__ f1T,
    __bf16* __restrict__ f2T) {
    __shared__ float tile[32][33];
    int bid = blockIdx.x;
    const float* in; __bf16* out; int N, nxs, ti;
    if (bid < 1024)      { in = Wq;  out = wqT;  N = 1024; nxs = 5; ti = bid; }
    else if (bid < 3072) { in = Wkv; out = wkvT; N = 2048; nxs = 6; ti = bid - 1024; }
    else if (bid < 4096) { in = Wout;out = woutT;N = 1024; nxs = 5; ti = bid - 3072; }
    else if (bid < 8192) { in = f1;  out = f1T;  N = 4096; nxs = 7; ti = bid - 4096; }
    else                 { in = f2;  out = f2T;  N = 1024; nxs = 5; ti = bid - 8192; }
    int K = (bid >= 8192) ? 4096 : 1024;
    int n0 = (ti & ((1 << nxs) - 1)) << 5;
    int k0 = (ti >> nxs) << 5;
    int tx = threadIdx.x & 31, ty = threadIdx.x >> 5;
#pragma unroll
    for (int p = 0; p < 4; ++p) {
        int kk = ty + p * 8;
        tile[kk][tx] = in[(size_t)(k0 + kk) * N + n0 + tx];
    }
    __syncthreads();
#pragma unroll
    for (int p = 0; p < 4; ++p) {
        int nn = ty + p * 8;
        out[(size_t)(n0 + nn) * K + k0 + tx] = f2bf(tile[tx][nn]);
    }
}

// ---------------- transpose + cast: in[K,N] f32 -> out[N,K] bf16 -----------
__global__ __launch_bounds__(256) void transpose_cast(const float* __restrict__ in,
                                                      __bf16* __restrict__ out,
                                                      int K, int N) {
    __shared__ float tile[32][33];
    int n0 = blockIdx.x * 32, k0 = blockIdx.y * 32;
    int tx = threadIdx.x & 31, ty = threadIdx.x >> 5;
#pragma unroll
    for (int p = 0; p < 4; ++p) {
        int kk = ty + p * 8;
        tile[kk][tx] = in[(size_t)(k0 + kk) * N + n0 + tx];
    }
    __syncthreads();
#pragma unroll
    for (int p = 0; p < 4; ++p) {
        int nn = ty + p * 8;
        out[(size_t)(n0 + nn) * K + k0 + tx] = f2bf(tile[tx][nn]);
    }
}

// ---------------- 128x128 MFMA GEMM (m97 structure) ------------------------
// EPI: 0=f32, 1=bf16, 2=bf16*scale, 3=gelu->f32
// split-K via blockIdx.z: A,Bt advance z*az cols; C slab = (z<zhalf?C0:C1)
//   + (z mod zhalf)*cz.
template <int EPI, bool POW2>
__global__ __launch_bounds__(256) void gemm_bf16(
    const __bf16* __restrict__ A, const __bf16* __restrict__ Bt,
    void* __restrict__ C0, void* __restrict__ C1, const float* __restrict__ bias,
    int M, int N, int K, int lda, int ldb, int brs, long long bstride, int ldc,
    float scale, int az, long long cz, int zhalf) {
    __shared__ __bf16 As[128][64];
    __shared__ __bf16 Bs[128][64];
    const int t = threadIdx.x;
    const int m0 = blockIdx.y * 128, n0 = blockIdx.x * 128;
    const int z = blockIdx.z;
    A += (size_t)z * az;
    Bt += (size_t)z * az;
    void* Cout = (z < zhalf) ? C0 : C1;
    const long long zoff = (long long)(z < zhalf ? z : z - zhalf) * cz;
    const int wid = t >> 6, lane = t & 63;
    const int wr = wid >> 1, wc = wid & 1;
    const int lrow = lane & 15;
    const int lr = lane >> 3, lc = lane & 7;
    const int src_col = (lc ^ lr) << 3;
    f32x4 acc[4][4] = {};

    int garow[4], gbrow[4];
#pragma unroll
    for (int it = 0; it < 4; ++it) {
        int r = wid * 8 + it * 32 + lr;
        int gm = m0 + r; garow[it] = gm < M ? gm : M - 1;
        int gn = n0 + r; gbrow[it] = gn < N ? gn : N - 1;
    }

    for (int kt = 0; kt < K; kt += 64) {
#pragma unroll
        for (int it = 0; it < 4; ++it) {
            int rb = wid * 8 + it * 32;
            gld_lds16(A + (size_t)garow[it] * lda + kt + src_col, &As[rb][0]);
            gld_lds16(Bt + (size_t)gbrow[it] * ldb + kt + src_col, &Bs[rb][0]);
        }
        __syncthreads();
#pragma unroll
        for (int kc = 0; kc < 2; ++kc) {
            const int ck = (kc << 2) + (lane >> 4);
            bf16x8 af[4], bfr[4];
#pragma unroll
            for (int f = 0; f < 4; ++f) {
                int ra = wr * 64 + f * 16 + lrow;
                af[f] = *(const bf16x8*)(&As[ra][(ck ^ (ra & 7)) << 3]);
                int rb = wc * 64 + f * 16 + lrow;
                bfr[f] = *(const bf16x8*)(&Bs[rb][(ck ^ (rb & 7)) << 3]);
            }
#pragma unroll
            for (int fm = 0; fm < 4; ++fm)
#pragma unroll
                for (int fn = 0; fn < 4; ++fn)
                    acc[fm][fn] = __builtin_amdgcn_mfma_f32_16x16x32_bf16(
                        af[fm], bfr[fn], acc[fm][fn], 0, 0, 0);
        }
        __syncthreads();
    }
    const int rbase = (lane >> 4) << 2;
    const int cofs = lane & 15;
    const int msk = POW2 ? (int)((1u << brs) - 1u) : 0;
#pragma unroll
    for (int fm = 0; fm < 4; ++fm) {
#pragma unroll
        for (int j = 0; j < 4; ++j) {
            int m = m0 + wr * 64 + fm * 16 + rbase + j;
            if (m >= M) continue;
            long long roff;
            if (POW2) roff = (long long)(m >> brs) * bstride + (long long)(m & msk) * ldc;
            else      roff = (long long)(m / brs) * bstride + (long long)(m % brs) * ldc;
            roff += zoff;
#pragma unroll
            for (int fn = 0; fn < 4; ++fn) {
                int n = n0 + wc * 64 + fn * 16 + cofs;
                if (n >= N) continue;
                float v = acc[fm][fn][j];
                if (bias) v += bias[n];
                if (EPI == 0) ((float*)Cout)[roff + n] = v;
                else if (EPI == 1) ((__bf16*)Cout)[roff + n] = f2bf(v);
                else if (EPI == 2) ((__bf16*)Cout)[roff + n] = f2bf(v * scale);
                else ((float*)Cout)[roff + n] = gelu_f(v);
            }
        }
    }
}

// ---------------- 256x256 8-phase counted-vmcnt GEMM (m201 port) -----------
// Used for the kv projection only (M=16384, 512 blocks = 2 clean rounds).
template <int EPI>
__global__ __launch_bounds__(512, 2) void gemm256(
    const __bf16* __restrict__ A, const __bf16* __restrict__ Bt,
    void* __restrict__ Cout, const float* __restrict__ bias,
    int M, int N, int K, int brs, long long bstride, int ldc, float scale,
    int gxs) {
    __shared__ __bf16 As[2][256][64];
    __shared__ __bf16 Bs[2][256][64];
    const int t = threadIdx.x;
    const int wid = t >> 6, lane = t & 63;
    const int wr = wid >> 2, wc = wid & 3;
    const int lrow = lane & 15, lk = lane >> 4;
    const int lr8 = lane >> 3;
    const int scol = ((lane & 7) ^ lr8) << 3;

    int nwg = gridDim.x;
    int L = blockIdx.x;
    if ((nwg & 7) == 0) L = (L & 7) * (nwg >> 3) + (L >> 3);
    const int bx = L & ((1 << gxs) - 1), by = L >> gxs;
    const int m0 = by * 256, n0 = bx * 256;

    unsigned aoff[4], boff[4];
#pragma unroll
    for (int h = 0; h < 2; ++h)
#pragma unroll
        for (int rnd = 0; rnd < 2; ++rnd) {
            int r = h * 128 + rnd * 64 + wid * 8 + lr8;
            int gm = m0 + r; if (gm > M - 1) gm = M - 1;
            aoff[h * 2 + rnd] = (unsigned)(gm * K + scol);
            int gn = n0 + r; if (gn > N - 1) gn = N - 1;
            boff[h * 2 + rnd] = (unsigned)(gn * K + scol);
        }

    auto stgA = [&](int buf, int tile, int h) {
        int kt = tile << 6;
        gld_lds16(A + aoff[h * 2 + 0] + kt, &As[buf][h * 128 + wid * 8][0]);
        gld_lds16(A + aoff[h * 2 + 1] + kt, &As[buf][h * 128 + 64 + wid * 8][0]);
    };
    auto stgB = [&](int buf, int tile, int h) {
        int kt = tile << 6;
        gld_lds16(Bt + boff[h * 2 + 0] + kt, &Bs[buf][h * 128 + wid * 8][0]);
        gld_lds16(Bt + boff[h * 2 + 1] + kt, &Bs[buf][h * 128 + 64 + wid * 8][0]);
    };

    f32x4 acc[8][4] = {};
    bf16x8 AF0[4][2], AF1[4][2], BF[2][2], BF2[2][2];

    auto rdAF = [&](bf16x8 (&AF)[4][2], int buf, int qm) {
#pragma unroll
        for (int i = 0; i < 4; ++i) {
            int ra = wr * 128 + (qm * 4 + i) * 16 + lrow;
            AF[i][0] = *(const bf16x8*)(&As[buf][ra][((lk) ^ (ra & 7)) << 3]);
            AF[i][1] = *(const bf16x8*)(&As[buf][ra][((4 + lk) ^ (ra & 7)) << 3]);
        }
    };
    auto rdBF = [&](bf16x8 (&BV)[2][2], int buf, int qn) {
#pragma unroll
        for (int i = 0; i < 2; ++i) {
            int rb = wc * 64 + (qn * 2 + i) * 16 + lrow;
            BV[i][0] = *(const bf16x8*)(&Bs[buf][rb][((lk) ^ (rb & 7)) << 3]);
            BV[i][1] = *(const bf16x8*)(&Bs[buf][rb][((4 + lk) ^ (rb & 7)) << 3]);
        }
    };
    auto mfq = [&](bf16x8 (&AF)[4][2], bf16x8 (&BV)[2][2], int mo, int no) {
        __builtin_amdgcn_s_setprio(1);
#pragma unroll
        for (int i = 0; i < 4; ++i)
#pragma unroll
            for (int nf = 0; nf < 2; ++nf)
#pragma unroll
                for (int ks = 0; ks < 2; ++ks)
                    acc[mo + i][no + nf] = __builtin_amdgcn_mfma_f32_16x16x32_bf16(
                        AF[i][ks], BV[nf][ks], acc[mo + i][no + nf], 0, 0, 0);
        __builtin_amdgcn_s_setprio(0);
    };

    const int nt = K >> 6;
    stgA(0, 0, 0); stgA(0, 0, 1);
    stgB(0, 0, 0); stgB(0, 0, 1);
    stgA(1, 1, 0); stgA(1, 1, 1);
    VMCNT4();
    SBAR();

    for (int tt = 0; tt < nt; tt += 2) {
        const int t1 = tt + 1;
        const int t2 = (tt + 2 < nt) ? tt + 2 : nt - 1;
        const int t3 = (tt + 3 < nt) ? tt + 3 : nt - 1;
        // P1
        rdAF(AF0, 0, 0); rdBF(BF, 0, 0);
        stgB(1, t1, 0);
        SBAR();
        mfq(AF0, BF, 0, 0);
        SBAR();
        // P2
        rdAF(AF1, 0, 1);
        stgB(1, t1, 1);
        SBAR();
        mfq(AF1, BF, 4, 0);
        SBAR();
        // P3
        rdBF(BF2, 0, 1);
        stgA(0, t2, 0);
        SBAR();
        mfq(AF1, BF2, 4, 2);
        SBAR();
        // P4
        stgA(0, t2, 1);
        SBAR();
        mfq(AF0, BF2, 0, 2);
        VMCNT4();
        SBAR();
        // P5
        rdAF(AF0, 1, 0); rdBF(BF, 1, 0);
        stgB(0, t2, 0);
        SBAR();
        mfq(AF0, BF, 0, 0);
        SBAR();
        // P6
        rdAF(AF1, 1, 1);
        stgB(0, t2, 1);
        SBAR();
        mfq(AF1, BF, 4, 0);
        SBAR();
        // P7
        rdBF(BF2, 1, 1);
        stgA(1, t3, 0);
        SBAR();
        mfq(AF1, BF2, 4, 2);
        SBAR();
        // P8
        stgA(1, t3, 1);
        SBAR();
        mfq(AF0, BF2, 0, 2);
        VMCNT4();
        SBAR();
    }

    const int rbase = (lane >> 4) << 2;
    const int cofs = lane & 15;
    const int msk = (int)((1u << brs) - 1u);
#pragma unroll
    for (int mf = 0; mf < 8; ++mf) {
#pragma unroll
        for (int j = 0; j < 4; ++j) {
            int m = m0 + wr * 128 + mf * 16 + rbase + j;
            if (m >= M) continue;
            long long roff = (long long)(m >> brs) * bstride +
                             (long long)(m & msk) * ldc;
#pragma unroll
            for (int nf = 0; nf < 4; ++nf) {
                int n = n0 + wc * 64 + nf * 16 + cofs;
                if (n >= N) continue;
                float v = acc[mf][nf][j];
                if (bias) v += bias[n];
                if (EPI == 1) ((__bf16*)Cout)[roff + n] = f2bf(v);
                else if (EPI == 3) ((float*)Cout)[roff + n] = gelu_f(v);
                else ((float*)Cout)[roff + n] = v;
            }
        }
    }
}

// ---------------- attention: S = Q @ K^T (MFMA) ----------------------------
__global__ __launch_bounds__(256) void qk_gemm(const __bf16* __restrict__ q,
                                               const __bf16* __restrict__ kv,
                                               __bf16* __restrict__ sp) {
    __shared__ __bf16 Qs[80][64];
    __shared__ __bf16 Ks[128][64];
    const int bh = blockIdx.x, b = bh >> 4, h = bh & 15;
    const int n0 = blockIdx.y * 128;
    const int t = threadIdx.x, wid = t >> 6, lane = t & 63;
    const __bf16* qbase = q + (size_t)b * LTOT * DIM + h * DH;
    const __bf16* kbase = kv + (size_t)b * KEYS * 2048 + h * DH;
    const bf16x8 zero8 = {};

    for (int s = t; s < 80 * 8; s += 256) {
        int r = s >> 3, c8 = s & 7;
        bf16x8 v = zero8;
        if (r < LTOT) v = *(const bf16x8*)(qbase + (size_t)r * DIM + (c8 << 3));
        *(bf16x8*)(&Qs[r][(c8 ^ (r & 7)) << 3]) = v;
    }
    for (int s = t; s < 128 * 8; s += 256) {
        int r = s >> 3, c8 = s & 7;
        int gk = n0 + r; if (gk >= KEYS) gk = KEYS - 1;
        bf16x8 v = *(const bf16x8*)(kbase + (size_t)gk * 2048 + (c8 << 3));
        *(bf16x8*)(&Ks[r][(c8 ^ (r & 7)) << 3]) = v;
    }
    __syncthreads();

    const int lrow = lane & 15;
    f32x4 acc[5][2] = {};
#pragma unroll
    for (int kc = 0; kc < 2; ++kc) {
        const int ck = (kc << 2) + (lane >> 4);
        bf16x8 bfr[2];
#pragma unroll
        for (int fn = 0; fn < 2; ++fn) {
            int rb = wid * 32 + fn * 16 + lrow;
            bfr[fn] = *(const bf16x8*)(&Ks[rb][(ck ^ (rb & 7)) << 3]);
        }
#pragma unroll
        for (int fm = 0; fm < 5; ++fm) {
            int ra = fm * 16 + lrow;
            bf16x8 af = *(const bf16x8*)(&Qs[ra][(ck ^ (ra & 7)) << 3]);
#pragma unroll
            for (int fn = 0; fn < 2; ++fn)
                acc[fm][fn] = __builtin_amdgcn_mfma_f32_16x16x32_bf16(
                    af, bfr[fn], acc[fm][fn], 0, 0, 0);
        }
    }
    __bf16* srow = sp + (size_t)bh * LTOT * KPAD;
    const int rbase = (lane >> 4) << 2, cofs = lane & 15;
#pragma unroll
    for (int fm = 0; fm < 5; ++fm)
#pragma unroll
        for (int j = 0; j < 4; ++j) {
            int r = fm * 16 + rbase + j;
            if (r >= LTOT) continue;
#pragma unroll
            for (int fn = 0; fn < 2; ++fn) {
                int col = n0 + wid * 32 + fn * 16 + cofs;
                srow[(size_t)r * KPAD + col] = f2bf(acc[fm][fn][j]);
            }
        }
}

// ---------------- row softmax in place, writes P/l, zeros for pad ----------
__global__ __launch_bounds__(256) void softmax_p(__bf16* __restrict__ sp) {
    const int row = blockIdx.x * 4 + (threadIdx.x >> 6);
    const int lane = threadIdx.x & 63;
    __bf16* p = sp + (size_t)row * KPAD;
    float v[10];
    float m = -3.0e38f;
#pragma unroll
    for (int i = 0; i < 10; ++i) {
        int c = (i << 6) + lane;
        float f = (c < KEYS) ? bf2f(p[c]) : -3.0e38f;
        v[i] = f; m = fmaxf(m, f);
    }
#pragma unroll
    for (int mk = 32; mk > 0; mk >>= 1) m = fmaxf(m, __shfl_xor(m, mk, 64));
    float l = 0.f;
#pragma unroll
    for (int i = 0; i < 10; ++i) {
        int c = (i << 6) + lane;
        float e = (c < KEYS) ? __expf(v[i] - m) : 0.f;
        v[i] = e; l += e;
    }
#pragma unroll
    for (int mk = 32; mk > 0; mk >>= 1) l += __shfl_xor(l, mk, 64);
    float inv = 1.f / l;
#pragma unroll
    for (int i = 0; i < 10; ++i) {
        int c = (i << 6) + lane;
        p[c] = f2bf(v[i] * inv);
    }
}

// ---------------- vt[bh][d][k] = v[b][k][h*64+d] ---------------------------
__global__ __launch_bounds__(256) void vt_tr(const __bf16* __restrict__ kv,
                                             __bf16* __restrict__ vt) {
    __shared__ __bf16 tile[32][34];
    const int bh = blockIdx.x, b = bh >> 4, h = bh & 15;
    const int k0 = blockIdx.y * 32, d0 = blockIdx.z * 32;
    const int tx = threadIdx.x & 31, ty = threadIdx.x >> 5;
    const __bf16* vbase = kv + (size_t)b * KEYS * 2048 + 1024 + h * DH;
#pragma unroll
    for (int p = 0; p < 4; ++p) {
        int kk = k0 + ty + p * 8;
        int kc = kk < KEYS ? kk : KEYS - 1;
        tile[ty + p * 8][tx] = vbase[(size_t)kc * 2048 + d0 + tx];
    }
    __syncthreads();
    __bf16* obase = vt + (size_t)bh * DH * KPAD;
#pragma unroll
    for (int p = 0; p < 4; ++p) {
        int nn = ty + p * 8;
        __bf16 val = (k0 + tx < KEYS) ? tile[tx][nn] : (__bf16)0.f;
        obase[(size_t)(d0 + nn) * KPAD + k0 + tx] = val;
    }
}

// ---------------- O = P @ V (MFMA), grid 512 bh ----------------------------
__global__ __launch_bounds__(256) void pv_gemm(const __bf16* __restrict__ sp,
                                               const __bf16* __restrict__ vt,
                                               __bf16* __restrict__ ao) {
    __shared__ __bf16 Ps[80][64];
    __shared__ __bf16 Vs[64][64];
    const int bh = blockIdx.x, b = bh >> 4, h = bh & 15;
    const int t = threadIdx.x, wid = t >> 6, lane = t & 63;
    const int lrow = lane & 15;
    const __bf16* pbase = sp + (size_t)bh * LTOT * KPAD;
    const __bf16* vbase = vt + (size_t)bh * DH * KPAD;
    const bf16x8 zero8 = {};
    f32x4 acc[5] = {};

    for (int kt = 0; kt < KPAD; kt += 64) {
        for (int s = t; s < 80 * 8; s += 256) {
            int r = s >> 3, c8 = s & 7;
            bf16x8 v = zero8;
            if (r < LTOT) v = *(const bf16x8*)(pbase + (size_t)r * KPAD + kt + (c8 << 3));
            *(bf16x8*)(&Ps[r][(c8 ^ (r & 7)) << 3]) = v;
        }
        for (int s = t; s < 64 * 8; s += 256) {
            int r = s >> 3, c8 = s & 7;
            bf16x8 v = *(const bf16x8*)(vbase + (size_t)r * KPAD + kt + (c8 << 3));
            *(bf16x8*)(&Vs[r][(c8 ^ (r & 7)) << 3]) = v;
        }
        __syncthreads();
#pragma unroll
        for (int kc = 0; kc < 2; ++kc) {
            const int ck = (kc << 2) + (lane >> 4);
            int rb = wid * 16 + lrow;
            bf16x8 bfr = *(const bf16x8*)(&Vs[rb][(ck ^ (rb & 7)) << 3]);
#pragma unroll
            for (int fm = 0; fm < 5; ++fm) {
                int ra = fm * 16 + lrow;
                bf16x8 af = *(const bf16x8*)(&Ps[ra][(ck ^ (ra & 7)) << 3]);
                acc[fm] = __builtin_amdgcn_mfma_f32_16x16x32_bf16(
                    af, bfr, acc[fm], 0, 0, 0);
            }
        }
        __syncthreads();
    }
    __bf16* obase = ao + (size_t)b * LTOT * DIM + h * DH;
    const int rbase = (lane >> 4) << 2, cofs = lane & 15;
#pragma unroll
    for (int fm = 0; fm < 5; ++fm)
#pragma unroll
        for (int j = 0; j < 4; ++j) {
            int r = fm * 16 + rbase + j;
            if (r >= LTOT) continue;
            obase[(size_t)r * DIM + wid * 16 + cofs] = f2bf(acc[fm][j]);
        }
}

// ---------------------------------------------------------------------------
template <int EPI, bool POW2>
static void g128(const __bf16* A, const __bf16* Bt, void* C0, void* C1,
                 const float* bias, int M, int N, int K, int lda, int ldb,
                 int brs, long long bs, int ldc, float scale, int gz, int az,
                 long long cz, int zhalf, hipStream_t s) {
    dim3 g(N / 128, (M + 127) / 128, gz);
    gemm_bf16<EPI, POW2><<<g, 256, 0, s>>>(A, Bt, C0, C1, bias, M, N, K, lda,
                                           ldb, brs, bs, ldc, scale, az, cz,
                                           zhalf);
}

extern "C" void kernel_launch(void* const* d_in, const int* in_sizes, int n_in,
                              void* d_out, int out_size, void* d_ws, size_t ws_size,
                              hipStream_t stream) {
    (void)in_sizes; (void)n_in; (void)out_size; (void)ws_size;
    const float* x          = (const float*)d_in[0];
    const float* pos_emb    = (const float*)d_in[2];
    const float* latents    = (const float*)d_in[3];
    const float* mp_ln_g    = (const float*)d_in[4];
    const float* mp_w       = (const float*)d_in[5];
    const float* mp_b       = (const float*)d_in[6];
    const float* attn_norm_w= (const float*)d_in[7];
    const float* attn_norm_b= (const float*)d_in[8];
    const float* attn_lat_w = (const float*)d_in[9];
    const float* attn_lat_b = (const float*)d_in[10];
    const float* Wq         = (const float*)d_in[11];
    const float* Wkv        = (const float*)d_in[12];
    const float* Wout       = (const float*)d_in[13];
    const float* out_ln_w   = (const float*)d_in[14];
    const float* out_ln_b   = (const float*)d_in[15];
    const float* ff_ln1_g   = (const float*)d_in[16];
    const float* ff_w1      = (const float*)d_in[17];
    const float* ff_ln2_g   = (const float*)d_in[18];
    const float* ff_w2      = (const float*)d_in[19];

    float* lat = (float*)d_out;                    // residual stream, f32

    char* ws = (char*)d_ws;
    size_t off = 0;
    auto take = [&](size_t bytes) -> char* {
        char* p = ws + off;
        off += (bytes + 255) & ~(size_t)255;
        return p;
    };
    __bf16* xpos = (__bf16*)take(2ULL * BATCH * SEQL * DIM);
    __bf16* xn   = (__bf16*)take(2ULL * BATCH * SEQL * DIM);
    __bf16* lnl  = (__bf16*)take(2ULL * BATCH * LTOT * DIM);
    __bf16* ffin = (__bf16*)take(2ULL * BATCH * LTOT * DIM);
    __bf16* qb   = (__bf16*)take(2ULL * BATCH * LTOT * DIM);
    __bf16* ao   = (__bf16*)take(2ULL * BATCH * LTOT * DIM);
    __bf16* kvb  = (__bf16*)take(2ULL * BATCH * KEYS * 2048);
    float*  gout = (float*)take(4ULL * MLAT * HID);           // 35.65 MB
    __bf16* h2   = (__bf16*)take(2ULL * MLAT * HID);          // 17.8 MB (contig)
    __bf16* vt   = (__bf16*)take(2ULL * BATCH * HEADS * DH * KPAD);  // 41.9 MB
    __bf16* wT   = (__bf16*)take(2ULL * 12 * 1024 * 1024);
    float*  pooled = (float*)take(4ULL * BATCH * DIM);
    __bf16* mpin = (__bf16*)take(2ULL * BATCH * DIM);

    // overlays (time-disjoint): sp = scores (qk..pv); vtf = f32 view of vt
    __bf16* sp = (__bf16*)gout;            // 44.6 MB spills into h2 region
    float*  vtf = (float*)vt;

    __bf16* wqT   = wT;                    // [1024,1024]
    __bf16* wkvT  = wT + 1 * 1024 * 1024;  // [2048,1024] (contig after wqT)
    __bf16* woutT = wT + 3 * 1024 * 1024;  // [1024,1024]
    __bf16* f1T   = wT + 4 * 1024 * 1024;  // [4096,1024]
    __bf16* f2T   = wT + 8 * 1024 * 1024;  // [1024,4096]
    __bf16* mpwT  = wT;                    // [4096,1024], used before layers

    // ---- prologue -----------------------------------------------------
    add_pos<<<4096, 256, 0, stream>>>(x, pos_emb, xpos);
    pool_mean<<<128, 256, 0, stream>>>(x, pooled);
    ln_rows<float, false, DIM><<<BATCH, 256, 0, stream>>>(pooled, mpin, mp_ln_g, nullptr);
    transpose_cast<<<dim3(128, 32), 256, 0, stream>>>(mp_w, mpwT, 1024, 4096);
    g128<0, true>(mpin, mpwT, lat, lat, mp_b, BATCH, 4096, 1024, 1024, 1024,
                  5, 0, LTOT * DIM, 1.f, 1, 0, 0, 1, stream);
    lat_fill<<<2048, 256, 0, stream>>>(latents, lat);

    // ---- layers -------------------------------------------------------
    for (int i = 0; i < 4; ++i) {
        transpose_all<<<12288, 256, 0, stream>>>(
            Wq + (size_t)i * 1024 * 1024, Wkv + (size_t)i * 1024 * 2048,
            Wout + (size_t)i * 1024 * 1024, ff_w1 + (size_t)i * 1024 * 4096,
            ff_w2 + (size_t)i * 4096 * 1024,
            wqT, wkvT, woutT, f1T, f2T);

        ln_rows<__bf16, true, DIM><<<BATCH * SEQL, 256, 0, stream>>>(
            xpos, xn, attn_norm_w + i * DIM, attn_norm_b + i * DIM);
        ln_rows<float, true, DIM><<<BATCH * LTOT, 256, 0, stream>>>(
            lat, lnl, attn_lat_w + i * DIM, attn_lat_b + i * DIM);

        // q + kv-tail in one GEMM: lnl @ [Wq|Wkv] (N=3072), split-K x2,
        // f32 partials -> gout..h2 (contig, 2 slabs of 26.75 MB)
        g128<0, true>(lnl, wqT, gout, gout, nullptr, MLAT, 3072, 512, 1024, 1024,
                      31, 0, 3072, 1.f, 2, 512, (long long)MLAT * 3072, 2, stream);
        qkv_red<<<dim3(3, MLAT), 256, 0, stream>>>(gout, qb, kvb);

        // kv rows 0..511 per batch from xn (256x256 8-phase kernel)
        gemm256<1><<<dim3(512), 512, 0, stream>>>(
            xn, wkvT, kvb, nullptr, BATCH * SEQL, 2048, 1024,
            9, (long long)KEYS * 2048, 2048, 1.f, 3);

        // ---- MFMA attention ----
        vt_tr<<<dim3(BATCH * HEADS, KPAD / 32, 2), 256, 0, stream>>>(kvb, vt);
        qk_gemm<<<dim3(BATCH * HEADS, KPAD / 128), 256, 0, stream>>>(qb, kvb, sp);
        softmax_p<<<(BATCH * HEADS * LTOT) / 4, 256, 0, stream>>>(sp);
        pv_gemm<<<BATCH * HEADS, 256, 0, stream>>>(sp, vt, ao);

        // wout split-K x4 -> 4 slabs in vt (free after pv)
        g128<0, true>(ao, woutT, vtf, vtf, nullptr, MLAT, 1024, 256, 1024, 1024,
                      31, 0, 1024, 1.f, 4, 256, (long long)MLAT * 1024, 4, stream);
        wout_ln_res<<<BATCH * LTOT, 256, 0, stream>>>(
            vtf, lat, ffin, out_ln_w + i * DIM, out_ln_b + i * DIM, ff_ln1_g + i * DIM);

        // ff1 split-K x2: slab0 -> gout (sp dead), slab1 -> vt (wout consumed)
        g128<0, true>(ffin, f1T, gout, vtf, nullptr, MLAT, HID, 512, 1024, 1024,
                      31, 0, HID, 1.f, 2, 512, 0, 1, stream);
        // reduce + gelu + custom LN -> h2
        ln_gelu2<<<BATCH * LTOT, 256, 0, stream>>>(gout, vtf, h2, ff_ln2_g + i * HID);

        // ff2 split-K x8: z0-3 -> gout, z4-7 -> vt
        g128<0, true>(h2, f2T, gout, vtf, nullptr, MLAT, 1024, 512, HID, HID,
                      31, 0, 1024, 1.f, 8, 512, (long long)MLAT * 1024, 4, stream);
        splitk_add8<<<MLAT, 256, 0, stream>>>(gout, vtf, lat);
    }
}

// Round 7
// 1658.639 us; speedup vs baseline: 1.3838x; 1.0620x over previous
//
#include <hip/hip_runtime.h>

// ---------------------------------------------------------------------------
// PerceiverResampler forward, MI355X gfx950.
// R7: split-K partial slabs stored as bf16 (halves partial HBM traffic);
//     reduce kernels (qkv_red, wout_ln_res, ln_gelu2, splitk_add8) read bf16.
// Residual stream (lat) lives in d_out (f32). Workspace ~261 MB.
// ---------------------------------------------------------------------------

typedef __attribute__((ext_vector_type(4))) float f32x4;
typedef __attribute__((ext_vector_type(8))) __bf16 bf16x8;
typedef __attribute__((ext_vector_type(4))) __bf16 bf16x4;

#define BATCH 32
#define SEQL  512
#define DIM   1024
#define HEADS 16
#define DH    64
#define LTOT  68          // 4 mean-pool latents + 64 learned
#define KEYS  580         // SEQL + LTOT
#define KPAD  640         // KEYS padded to 5*128
#define HID   4096
#define LN_EPS 1e-5f
#define MLAT  2176        // BATCH * LTOT

__device__ __forceinline__ float bf2f(__bf16 v) { return (float)v; }
__device__ __forceinline__ __bf16 f2bf(float v) { return (__bf16)v; }
__device__ __forceinline__ float gelu_f(float v) {
    return 0.5f * v * (1.0f + erff(v * 0.70710678118654752f));
}

// async 16B global -> LDS (wave-uniform LDS base + lane*16)
__device__ __forceinline__ void gld_lds16(const __bf16* g, __bf16* l) {
    __builtin_amdgcn_global_load_lds(
        (const __attribute__((address_space(1))) void*)g,
        (__attribute__((address_space(3))) void*)l, 16, 0, 0);
}

#define SBAR()   asm volatile("s_barrier" ::: "memory")
#define VMCNT4() asm volatile("s_waitcnt vmcnt(4)" ::: "memory")

// ---------------- block-wide 2-value sum reduction (256 threads) ------------
__device__ __forceinline__ void block_reduce2(float& a, float& b, float* red) {
#pragma unroll
    for (int m = 32; m > 0; m >>= 1) {
        a += __shfl_xor(a, m, 64);
        b += __shfl_xor(b, m, 64);
    }
    int wid = threadIdx.x >> 6, lane = threadIdx.x & 63;
    __syncthreads();
    if (lane == 0) { red[wid] = a; red[4 + wid] = b; }
    __syncthreads();
    a = red[0] + red[1] + red[2] + red[3];
    b = red[4] + red[5] + red[6] + red[7];
}

// ---------------- x_pos = bf16(x + pos_emb) --------------------------------
__global__ __launch_bounds__(256) void add_pos(const float* __restrict__ x,
                                               const float* __restrict__ pos,
                                               __bf16* __restrict__ xp) {
    const int total4 = (BATCH * SEQL * DIM) / 4;
    const int pos4m = (SEQL * DIM) / 4 - 1;
    for (int i = blockIdx.x * 256 + threadIdx.x; i < total4; i += gridDim.x * 256) {
        f32x4 xv = ((const f32x4*)x)[i];
        f32x4 pv = ((const f32x4*)pos)[i & pos4m];
        bf16x4 o;
#pragma unroll
        for (int j = 0; j < 4; ++j) o[j] = f2bf(xv[j] + pv[j]);
        ((bf16x4*)xp)[i] = o;
    }
}

// ---------------- pooled[b][d] = mean_s x[b,s,d] ---------------------------
__global__ __launch_bounds__(256) void pool_mean(const float* __restrict__ x,
                                                 float* __restrict__ pooled) {
    int b = blockIdx.x >> 2;
    int d = ((blockIdx.x & 3) << 8) + threadIdx.x;
    const float* p = x + (size_t)b * SEQL * DIM + d;
    float s = 0.f;
    for (int ss = 0; ss < SEQL; ++ss) s += p[(size_t)ss * DIM];
    pooled[b * DIM + d] = s * (1.f / SEQL);
}

// ---------------- lat rows 4..67 = latents ---------------------------------
__global__ __launch_bounds__(256) void lat_fill(const float* __restrict__ latents,
                                                float* __restrict__ lat) {
    int i = blockIdx.x * 256 + threadIdx.x;
    int b = i >> 14;
    int rem = i & 16383;
    int r = rem >> 8, d4 = rem & 255;
    ((f32x4*)lat)[(size_t)(b * LTOT + 4 + r) * 256 + d4] = ((const f32x4*)latents)[rem];
}

// ---------------- row LayerNorm -> bf16 (vectorized) ------------------------
template <typename Tin, bool STD, int COLS>
__global__ __launch_bounds__(256) void ln_rows(const Tin* __restrict__ in,
                                               __bf16* __restrict__ out,
                                               const float* __restrict__ w,
                                               const float* __restrict__ bb) {
    __shared__ float red[8];
    constexpr int NPT = COLS / 256;
    size_t base = (size_t)blockIdx.x * COLS;
    int t = threadIdx.x;
    int c0 = t * NPT;
    float xv[NPT];
    float s = 0.f, s2 = 0.f;
#pragma unroll
    for (int k4 = 0; k4 < NPT / 4; ++k4) {
        if constexpr (sizeof(Tin) == 2) {
            bf16x4 v = *(const bf16x4*)(in + base + c0 + k4 * 4);
#pragma unroll
            for (int e = 0; e < 4; ++e) {
                float f = bf2f(v[e]);
                xv[k4 * 4 + e] = f; s += f; s2 += f * f;
            }
        } else {
            f32x4 v = *(const f32x4*)((const float*)in + base + c0 + k4 * 4);
#pragma unroll
            for (int e = 0; e < 4; ++e) {
                float f = v[e];
                xv[k4 * 4 + e] = f; s += f; s2 += f * f;
            }
        }
    }
    block_reduce2(s, s2, red);
    float mean = s * (1.f / COLS);
    float var = s2 * (1.f / COLS) - mean * mean;
    float rstd = rsqrtf(var + LN_EPS);
#pragma unroll
    for (int k4 = 0; k4 < NPT / 4; ++k4) {
        f32x4 wv = *(const f32x4*)(w + c0 + k4 * 4);
        f32x4 bv;
        if (STD) bv = *(const f32x4*)(bb + c0 + k4 * 4);
        bf16x4 o;
#pragma unroll
        for (int e = 0; e < 4; ++e) {
            float y = (xv[k4 * 4 + e] - mean) * rstd * wv[e];
            if (STD) y += bv[e];
            o[e] = f2bf(y);
        }
        *(bf16x4*)(out + base + c0 + k4 * 4) = o;
    }
}

// ----- ff1 reduce (2 bf16 slabs) + gelu + custom LN: h2 = ln(gelu(a+b))*g --
__global__ __launch_bounds__(256) void ln_gelu2(const __bf16* __restrict__ pk,
                                                __bf16* __restrict__ out,
                                                const float* __restrict__ g) {
    __shared__ float red[8];
    constexpr int NPT = HID / 256;   // 16
    const size_t S = (size_t)MLAT * HID;
    size_t base = (size_t)blockIdx.x * HID;
    int t = threadIdx.x;
    int c0 = t * NPT;
    float xv[NPT];
    float s = 0.f, s2 = 0.f;
#pragma unroll
    for (int k4 = 0; k4 < NPT / 4; ++k4) {
        bf16x4 va = *(const bf16x4*)(pk + base + c0 + k4 * 4);
        bf16x4 vb = *(const bf16x4*)(pk + S + base + c0 + k4 * 4);
#pragma unroll
        for (int e = 0; e < 4; ++e) {
            float f = gelu_f(bf2f(va[e]) + bf2f(vb[e]));
            xv[k4 * 4 + e] = f; s += f; s2 += f * f;
        }
    }
    block_reduce2(s, s2, red);
    float mean = s * (1.f / HID);
    float var = s2 * (1.f / HID) - mean * mean;
    float rstd = rsqrtf(var + LN_EPS);
#pragma unroll
    for (int k4 = 0; k4 < NPT / 4; ++k4) {
        f32x4 gv = *(const f32x4*)(g + c0 + k4 * 4);
        bf16x4 o;
#pragma unroll
        for (int e = 0; e < 4; ++e)
            o[e] = f2bf((xv[k4 * 4 + e] - mean) * rstd * gv[e]);
        *(bf16x4*)(out + base + c0 + k4 * 4) = o;
    }
}

// -- wout 4-bf16-slab reduce; lat = std_ln(sum)*w+b + lat; ffin = c_ln*g1 ---
__global__ __launch_bounds__(256) void wout_ln_res(const __bf16* __restrict__ gin,
                                                   float* __restrict__ lat,
                                                   __bf16* __restrict__ ffin,
                                                   const float* __restrict__ w,
                                                   const float* __restrict__ b,
                                                   const float* __restrict__ g1) {
    __shared__ float red[8];
    const size_t SL = (size_t)MLAT * DIM;
    size_t base = (size_t)blockIdx.x * DIM;
    int t = threadIdx.x;
    float xv[4];
    float s = 0.f, s2 = 0.f;
#pragma unroll
    for (int k = 0; k < 4; ++k) {
        size_t idx = base + t + (k << 8);
        float v = bf2f(gin[idx]) + bf2f(gin[idx + SL]) +
                  bf2f(gin[idx + 2 * SL]) + bf2f(gin[idx + 3 * SL]);
        xv[k] = v; s += v; s2 += v * v;
    }
    block_reduce2(s, s2, red);
    float mean = s * (1.f / DIM);
    float var = s2 * (1.f / DIM) - mean * mean;
    float rstd = rsqrtf(var + LN_EPS);
    float yv[4];
    s = 0.f; s2 = 0.f;
#pragma unroll
    for (int k = 0; k < 4; ++k) {
        int c = t + (k << 8);
        float y = (xv[k] - mean) * rstd * w[c] + b[c] + lat[base + c];
        yv[k] = y; s += y; s2 += y * y;
        lat[base + c] = y;
    }
    block_reduce2(s, s2, red);
    float mean2 = s * (1.f / DIM);
    float var2 = s2 * (1.f / DIM) - mean2 * mean2;
    float rstd2 = rsqrtf(var2 + LN_EPS);
#pragma unroll
    for (int k = 0; k < 4; ++k) {
        int c = t + (k << 8);
        ffin[base + c] = f2bf((yv[k] - mean2) * rstd2 * g1[c]);
    }
}

// ---------------- qkv reduce: 2 bf16 slabs -> qb (*0.125) / kvb tail -------
__global__ __launch_bounds__(256) void qkv_red(const __bf16* __restrict__ pk,
                                               __bf16* __restrict__ qb,
                                               __bf16* __restrict__ kvb) {
    const size_t S = (size_t)MLAT * 3072;
    int row = blockIdx.y;
    int n = (blockIdx.x * 256 + threadIdx.x) * 4;
    size_t idx = (size_t)row * 3072 + n;
    bf16x4 a = *(const bf16x4*)(pk + idx);
    bf16x4 b = *(const bf16x4*)(pk + S + idx);
    bf16x4 o;
    if (n < 1024) {
#pragma unroll
        for (int e = 0; e < 4; ++e) o[e] = f2bf((bf2f(a[e]) + bf2f(b[e])) * 0.125f);
        *(bf16x4*)(qb + (size_t)row * 1024 + n) = o;
    } else {
#pragma unroll
        for (int e = 0; e < 4; ++e) o[e] = f2bf(bf2f(a[e]) + bf2f(b[e]));
        int bb = ((row >> 2) * 61681) >> 20;       // row / 68
        int r = row - bb * 68;
        *(bf16x4*)(kvb + (size_t)bb * KEYS * 2048 + (size_t)(512 + r) * 2048 +
                   (n - 1024)) = o;
    }
}

// ---------------- ff2 reduce: lat += sum of 8 bf16 slabs -------------------
__global__ __launch_bounds__(256) void splitk_add8(const __bf16* __restrict__ p,
                                                   float* __restrict__ lat) {
    const size_t S = (size_t)MLAT * 1024;
    int i = blockIdx.x * 256 + threadIdx.x;      // f32x4 index
    size_t e0 = (size_t)i * 4;
    f32x4 acc = ((f32x4*)lat)[i];
#pragma unroll
    for (int s = 0; s < 8; ++s) {
        bf16x4 v = *(const bf16x4*)(p + s * S + e0);
#pragma unroll
        for (int e = 0; e < 4; ++e) acc[e] += bf2f(v[e]);
    }
    ((f32x4*)lat)[i] = acc;
}

// ---------------- all 5 weight transposes for one layer in one launch ------
__global__ __launch_bounds__(256) void transpose_all(
    const float* __restrict__ Wq, const float* __restrict__ Wkv,
    const float* __restrict__ Wout, const float* __restrict__ f1,
    const float* __restrict__ f2,
    __bf16* __restrict__ wqT, __bf16* __restrict__ wkvT,
    __bf16* __restrict__ woutT, __bf16* __restrict__ f1T,
    __bf16* __restrict__ f2T) {
    __shared__ float tile[32][33];
    int bid = blockIdx.x;
    const float* in; __bf16* out; int N, nxs, ti;
    if (bid < 1024)      { in = Wq;  out = wqT;  N = 1024; nxs = 5; ti = bid; }
    else if (bid < 3072) { in = Wkv; out = wkvT; N = 2048; nxs = 6; ti = bid - 1024; }
    else if (bid < 4096) { in = Wout;out = woutT;N = 1024; nxs = 5; ti = bid - 3072; }
    else if (bid < 8192) { in = f1;  out = f1T;  N = 4096; nxs = 7; ti = bid - 4096; }
    else                 { in = f2;  out = f2T;  N = 1024; nxs = 5; ti = bid - 8192; }
    int K = (bid >= 8192) ? 4096 : 1024;
    int n0 = (ti & ((1 << nxs) - 1)) << 5;
    int k0 = (ti >> nxs) << 5;
    int tx = threadIdx.x & 31, ty = threadIdx.x >> 5;
#pragma unroll
    for (int p = 0; p < 4; ++p) {
        int kk = ty + p * 8;
        tile[kk][tx] = in[(size_t)(k0 + kk) * N + n0 + tx];
    }
    __syncthreads();
#pragma unroll
    for (int p = 0; p < 4; ++p) {
        int nn = ty + p * 8;
        out[(size_t)(n0 + nn) * K + k0 + tx] = f2bf(tile[tx][nn]);
    }
}

// ---------------- transpose + cast: in[K,N] f32 -> out[N,K] bf16 -----------
__global__ __launch_bounds__(256) void transpose_cast(const float* __restrict__ in,
                                                      __bf16* __restrict__ out,
                                                      int K, int N) {
    __shared__ float tile[32][33];
    int n0 = blockIdx.x * 32, k0 = blockIdx.y * 32;
    int tx = threadIdx.x & 31, ty = threadIdx.x >> 5;
#pragma unroll
    for (int p = 0; p < 4; ++p) {
        int kk = ty + p * 8;
        tile[kk][tx] = in[(size_t)(k0 + kk) * N + n0 + tx];
    }
    __syncthreads();
#pragma unroll
    for (int p = 0; p < 4; ++p) {
        int nn = ty + p * 8;
        out[(size_t)(n0 + nn) * K + k0 + tx] = f2bf(tile[tx][nn]);
    }
}

// ---------------- 128x128 MFMA GEMM (m97 structure) ------------------------
// EPI: 0=f32, 1=bf16, 2=bf16*scale, 3=gelu->f32
// split-K via blockIdx.z: A,Bt advance z*az cols; C slab = (z<zhalf?C0:C1)
//   + (z mod zhalf)*cz (cz in ELEMENTS of the output type).
template <int EPI, bool POW2>
__global__ __launch_bounds__(256) void gemm_bf16(
    const __bf16* __restrict__ A, const __bf16* __restrict__ Bt,
    void* __restrict__ C0, void* __restrict__ C1, const float* __restrict__ bias,
    int M, int N, int K, int lda, int ldb, int brs, long long bstride, int ldc,
    float scale, int az, long long cz, int zhalf) {
    __shared__ __bf16 As[128][64];
    __shared__ __bf16 Bs[128][64];
    const int t = threadIdx.x;
    const int m0 = blockIdx.y * 128, n0 = blockIdx.x * 128;
    const int z = blockIdx.z;
    A += (size_t)z * az;
    Bt += (size_t)z * az;
    void* Cout = (z < zhalf) ? C0 : C1;
    const long long zoff = (long long)(z < zhalf ? z : z - zhalf) * cz;
    const int wid = t >> 6, lane = t & 63;
    const int wr = wid >> 1, wc = wid & 1;
    const int lrow = lane & 15;
    const int lr = lane >> 3, lc = lane & 7;
    const int src_col = (lc ^ lr) << 3;
    f32x4 acc[4][4] = {};

    int garow[4], gbrow[4];
#pragma unroll
    for (int it = 0; it < 4; ++it) {
        int r = wid * 8 + it * 32 + lr;
        int gm = m0 + r; garow[it] = gm < M ? gm : M - 1;
        int gn = n0 + r; gbrow[it] = gn < N ? gn : N - 1;
    }

    for (int kt = 0; kt < K; kt += 64) {
#pragma unroll
        for (int it = 0; it < 4; ++it) {
            int rb = wid * 8 + it * 32;
            gld_lds16(A + (size_t)garow[it] * lda + kt + src_col, &As[rb][0]);
            gld_lds16(Bt + (size_t)gbrow[it] * ldb + kt + src_col, &Bs[rb][0]);
        }
        __syncthreads();
#pragma unroll
        for (int kc = 0; kc < 2; ++kc) {
            const int ck = (kc << 2) + (lane >> 4);
            bf16x8 af[4], bfr[4];
#pragma unroll
            for (int f = 0; f < 4; ++f) {
                int ra = wr * 64 + f * 16 + lrow;
                af[f] = *(const bf16x8*)(&As[ra][(ck ^ (ra & 7)) << 3]);
                int rb = wc * 64 + f * 16 + lrow;
                bfr[f] = *(const bf16x8*)(&Bs[rb][(ck ^ (rb & 7)) << 3]);
            }
#pragma unroll
            for (int fm = 0; fm < 4; ++fm)
#pragma unroll
                for (int fn = 0; fn < 4; ++fn)
                    acc[fm][fn] = __builtin_amdgcn_mfma_f32_16x16x32_bf16(
                        af[fm], bfr[fn], acc[fm][fn], 0, 0, 0);
        }
        __syncthreads();
    }
    const int rbase = (lane >> 4) << 2;
    const int cofs = lane & 15;
    const int msk = POW2 ? (int)((1u << brs) - 1u) : 0;
#pragma unroll
    for (int fm = 0; fm < 4; ++fm) {
#pragma unroll
        for (int j = 0; j < 4; ++j) {
            int m = m0 + wr * 64 + fm * 16 + rbase + j;
            if (m >= M) continue;
            long long roff;
            if (POW2) roff = (long long)(m >> brs) * bstride + (long long)(m & msk) * ldc;
            else      roff = (long long)(m / brs) * bstride + (long long)(m % brs) * ldc;
            roff += zoff;
#pragma unroll
            for (int fn = 0; fn < 4; ++fn) {
                int n = n0 + wc * 64 + fn * 16 + cofs;
                if (n >= N) continue;
                float v = acc[fm][fn][j];
                if (bias) v += bias[n];
                if (EPI == 0) ((float*)Cout)[roff + n] = v;
                else if (EPI == 1) ((__bf16*)Cout)[roff + n] = f2bf(v);
                else if (EPI == 2) ((__bf16*)Cout)[roff + n] = f2bf(v * scale);
                else ((float*)Cout)[roff + n] = gelu_f(v);
            }
        }
    }
}

// ---------------- 256x256 8-phase counted-vmcnt GEMM (m201 port) -----------
// Used for the kv projection only (M=16384, 512 blocks = 2 clean rounds).
template <int EPI>
__global__ __launch_bounds__(512, 2) void gemm256(
    const __bf16* __restrict__ A, const __bf16* __restrict__ Bt,
    void* __restrict__ Cout, const float* __restrict__ bias,
    int M, int N, int K, int brs, long long bstride, int ldc, float scale,
    int gxs) {
    __shared__ __bf16 As[2][256][64];
    __shared__ __bf16 Bs[2][256][64];
    const int t = threadIdx.x;
    const int wid = t >> 6, lane = t & 63;
    const int wr = wid >> 2, wc = wid & 3;
    const int lrow = lane & 15, lk = lane >> 4;
    const int lr8 = lane >> 3;
    const int scol = ((lane & 7) ^ lr8) << 3;

    int nwg = gridDim.x;
    int L = blockIdx.x;
    if ((nwg & 7) == 0) L = (L & 7) * (nwg >> 3) + (L >> 3);
    const int bx = L & ((1 << gxs) - 1), by = L >> gxs;
    const int m0 = by * 256, n0 = bx * 256;

    unsigned aoff[4], boff[4];
#pragma unroll
    for (int h = 0; h < 2; ++h)
#pragma unroll
        for (int rnd = 0; rnd < 2; ++rnd) {
            int r = h * 128 + rnd * 64 + wid * 8 + lr8;
            int gm = m0 + r; if (gm > M - 1) gm = M - 1;
            aoff[h * 2 + rnd] = (unsigned)(gm * K + scol);
            int gn = n0 + r; if (gn > N - 1) gn = N - 1;
            boff[h * 2 + rnd] = (unsigned)(gn * K + scol);
        }

    auto stgA = [&](int buf, int tile, int h) {
        int kt = tile << 6;
        gld_lds16(A + aoff[h * 2 + 0] + kt, &As[buf][h * 128 + wid * 8][0]);
        gld_lds16(A + aoff[h * 2 + 1] + kt, &As[buf][h * 128 + 64 + wid * 8][0]);
    };
    auto stgB = [&](int buf, int tile, int h) {
        int kt = tile << 6;
        gld_lds16(Bt + boff[h * 2 + 0] + kt, &Bs[buf][h * 128 + wid * 8][0]);
        gld_lds16(Bt + boff[h * 2 + 1] + kt, &Bs[buf][h * 128 + 64 + wid * 8][0]);
    };

    f32x4 acc[8][4] = {};
    bf16x8 AF0[4][2], AF1[4][2], BF[2][2], BF2[2][2];

    auto rdAF = [&](bf16x8 (&AF)[4][2], int buf, int qm) {
#pragma unroll
        for (int i = 0; i < 4; ++i) {
            int ra = wr * 128 + (qm * 4 + i) * 16 + lrow;
            AF[i][0] = *(const bf16x8*)(&As[buf][ra][((lk) ^ (ra & 7)) << 3]);
            AF[i][1] = *(const bf16x8*)(&As[buf][ra][((4 + lk) ^ (ra & 7)) << 3]);
        }
    };
    auto rdBF = [&](bf16x8 (&BV)[2][2], int buf, int qn) {
#pragma unroll
        for (int i = 0; i < 2; ++i) {
            int rb = wc * 64 + (qn * 2 + i) * 16 + lrow;
            BV[i][0] = *(const bf16x8*)(&Bs[buf][rb][((lk) ^ (rb & 7)) << 3]);
            BV[i][1] = *(const bf16x8*)(&Bs[buf][rb][((4 + lk) ^ (rb & 7)) << 3]);
        }
    };
    auto mfq = [&](bf16x8 (&AF)[4][2], bf16x8 (&BV)[2][2], int mo, int no) {
        __builtin_amdgcn_s_setprio(1);
#pragma unroll
        for (int i = 0; i < 4; ++i)
#pragma unroll
            for (int nf = 0; nf < 2; ++nf)
#pragma unroll
                for (int ks = 0; ks < 2; ++ks)
                    acc[mo + i][no + nf] = __builtin_amdgcn_mfma_f32_16x16x32_bf16(
                        AF[i][ks], BV[nf][ks], acc[mo + i][no + nf], 0, 0, 0);
        __builtin_amdgcn_s_setprio(0);
    };

    const int nt = K >> 6;
    stgA(0, 0, 0); stgA(0, 0, 1);
    stgB(0, 0, 0); stgB(0, 0, 1);
    stgA(1, 1, 0); stgA(1, 1, 1);
    VMCNT4();
    SBAR();

    for (int tt = 0; tt < nt; tt += 2) {
        const int t1 = tt + 1;
        const int t2 = (tt + 2 < nt) ? tt + 2 : nt - 1;
        const int t3 = (tt + 3 < nt) ? tt + 3 : nt - 1;
        // P1
        rdAF(AF0, 0, 0); rdBF(BF, 0, 0);
        stgB(1, t1, 0);
        SBAR();
        mfq(AF0, BF, 0, 0);
        SBAR();
        // P2
        rdAF(AF1, 0, 1);
        stgB(1, t1, 1);
        SBAR();
        mfq(AF1, BF, 4, 0);
        SBAR();
        // P3
        rdBF(BF2, 0, 1);
        stgA(0, t2, 0);
        SBAR();
        mfq(AF1, BF2, 4, 2);
        SBAR();
        // P4
        stgA(0, t2, 1);
        SBAR();
        mfq(AF0, BF2, 0, 2);
        VMCNT4();
        SBAR();
        // P5
        rdAF(AF0, 1, 0); rdBF(BF, 1, 0);
        stgB(0, t2, 0);
        SBAR();
        mfq(AF0, BF, 0, 0);
        SBAR();
        // P6
        rdAF(AF1, 1, 1);
        stgB(0, t2, 1);
        SBAR();
        mfq(AF1, BF, 4, 0);
        SBAR();
        // P7
        rdBF(BF2, 1, 1);
        stgA(1, t3, 0);
        SBAR();
        mfq(AF1, BF2, 4, 2);
        SBAR();
        // P8
        stgA(1, t3, 1);
        SBAR();
        mfq(AF0, BF2, 0, 2);
        VMCNT4();
        SBAR();
    }

    const int rbase = (lane >> 4) << 2;
    const int cofs = lane & 15;
    const int msk = (int)((1u << brs) - 1u);
#pragma unroll
    for (int mf = 0; mf < 8; ++mf) {
#pragma unroll
        for (int j = 0; j < 4; ++j) {
            int m = m0 + wr * 128 + mf * 16 + rbase + j;
            if (m >= M) continue;
            long long roff = (long long)(m >> brs) * bstride +
                             (long long)(m & msk) * ldc;
#pragma unroll
            for (int nf = 0; nf < 4; ++nf) {
                int n = n0 + wc * 64 + nf * 16 + cofs;
                if (n >= N) continue;
                float v = acc[mf][nf][j];
                if (bias) v += bias[n];
                if (EPI == 1) ((__bf16*)Cout)[roff + n] = f2bf(v);
                else if (EPI == 3) ((float*)Cout)[roff + n] = gelu_f(v);
                else ((float*)Cout)[roff + n] = v;
            }
        }
    }
}

// ---------------- attention: S = Q @ K^T (MFMA) ----------------------------
__global__ __launch_bounds__(256) void qk_gemm(const __bf16* __restrict__ q,
                                               const __bf16* __restrict__ kv,
                                               __bf16* __restrict__ sp) {
    __shared__ __bf16 Qs[80][64];
    __shared__ __bf16 Ks[128][64];
    const int bh = blockIdx.x, b = bh >> 4, h = bh & 15;
    const int n0 = blockIdx.y * 128;
    const int t = threadIdx.x, wid = t >> 6, lane = t & 63;
    const __bf16* qbase = q + (size_t)b * LTOT * DIM + h * DH;
    const __bf16* kbase = kv + (size_t)b * KEYS * 2048 + h * DH;
    const bf16x8 zero8 = {};

    for (int s = t; s < 80 * 8; s += 256) {
        int r = s >> 3, c8 = s & 7;
        bf16x8 v = zero8;
        if (r < LTOT) v = *(const bf16x8*)(qbase + (size_t)r * DIM + (c8 << 3));
        *(bf16x8*)(&Qs[r][(c8 ^ (r & 7)) << 3]) = v;
    }
    for (int s = t; s < 128 * 8; s += 256) {
        int r = s >> 3, c8 = s & 7;
        int gk = n0 + r; if (gk >= KEYS) gk = KEYS - 1;
        bf16x8 v = *(const bf16x8*)(kbase + (size_t)gk * 2048 + (c8 << 3));
        *(bf16x8*)(&Ks[r][(c8 ^ (r & 7)) << 3]) = v;
    }
    __syncthreads();

    const int lrow = lane & 15;
    f32x4 acc[5][2] = {};
#pragma unroll
    for (int kc = 0; kc < 2; ++kc) {
        const int ck = (kc << 2) + (lane >> 4);
        bf16x8 bfr[2];
#pragma unroll
        for (int fn = 0; fn < 2; ++fn) {
            int rb = wid * 32 + fn * 16 + lrow;
            bfr[fn] = *(const bf16x8*)(&Ks[rb][(ck ^ (rb & 7)) << 3]);
        }
#pragma unroll
        for (int fm = 0; fm < 5; ++fm) {
            int ra = fm * 16 + lrow;
            bf16x8 af = *(const bf16x8*)(&Qs[ra][(ck ^ (ra & 7)) << 3]);
#pragma unroll
            for (int fn = 0; fn < 2; ++fn)
                acc[fm][fn] = __builtin_amdgcn_mfma_f32_16x16x32_bf16(
                    af, bfr[fn], acc[fm][fn], 0, 0, 0);
        }
    }
    __bf16* srow = sp + (size_t)bh * LTOT * KPAD;
    const int rbase = (lane >> 4) << 2, cofs = lane & 15;
#pragma unroll
    for (int fm = 0; fm < 5; ++fm)
#pragma unroll
        for (int j = 0; j < 4; ++j) {
            int r = fm * 16 + rbase + j;
            if (r >= LTOT) continue;
#pragma unroll
            for (int fn = 0; fn < 2; ++fn) {
                int col = n0 + wid * 32 + fn * 16 + cofs;
                srow[(size_t)r * KPAD + col] = f2bf(acc[fm][fn][j]);
            }
        }
}

// ---------------- row softmax in place, writes P/l, zeros for pad ----------
__global__ __launch_bounds__(256) void softmax_p(__bf16* __restrict__ sp) {
    const int row = blockIdx.x * 4 + (threadIdx.x >> 6);
    const int lane = threadIdx.x & 63;
    __bf16* p = sp + (size_t)row * KPAD;
    float v[10];
    float m = -3.0e38f;
#pragma unroll
    for (int i = 0; i < 10; ++i) {
        int c = (i << 6) + lane;
        float f = (c < KEYS) ? bf2f(p[c]) : -3.0e38f;
        v[i] = f; m = fmaxf(m, f);
    }
#pragma unroll
    for (int mk = 32; mk > 0; mk >>= 1) m = fmaxf(m, __shfl_xor(m, mk, 64));
    float l = 0.f;
#pragma unroll
    for (int i = 0; i < 10; ++i) {
        int c = (i << 6) + lane;
        float e = (c < KEYS) ? __expf(v[i] - m) : 0.f;
        v[i] = e; l += e;
    }
#pragma unroll
    for (int mk = 32; mk > 0; mk >>= 1) l += __shfl_xor(l, mk, 64);
    float inv = 1.f / l;
#pragma unroll
    for (int i = 0; i < 10; ++i) {
        int c = (i << 6) + lane;
        p[c] = f2bf(v[i] * inv);
    }
}

// ---------------- vt[bh][d][k] = v[b][k][h*64+d] ---------------------------
__global__ __launch_bounds__(256) void vt_tr(const __bf16* __restrict__ kv,
                                             __bf16* __restrict__ vt) {
    __shared__ __bf16 tile[32][34];
    const int bh = blockIdx.x, b = bh >> 4, h = bh & 15;
    const int k0 = blockIdx.y * 32, d0 = blockIdx.z * 32;
    const int tx = threadIdx.x & 31, ty = threadIdx.x >> 5;
    const __bf16* vbase = kv + (size_t)b * KEYS * 2048 + 1024 + h * DH;
#pragma unroll
    for (int p = 0; p < 4; ++p) {
        int kk = k0 + ty + p * 8;
        int kc = kk < KEYS ? kk : KEYS - 1;
        tile[ty + p * 8][tx] = vbase[(size_t)kc * 2048 + d0 + tx];
    }
    __syncthreads();
    __bf16* obase = vt + (size_t)bh * DH * KPAD;
#pragma unroll
    for (int p = 0; p < 4; ++p) {
        int nn = ty + p * 8;
        __bf16 val = (k0 + tx < KEYS) ? tile[tx][nn] : (__bf16)0.f;
        obase[(size_t)(d0 + nn) * KPAD + k0 + tx] = val;
    }
}

// ---------------- O = P @ V (MFMA), grid 512 bh ----------------------------
__global__ __launch_bounds__(256) void pv_gemm(const __bf16* __restrict__ sp,
                                               const __bf16* __restrict__ vt,
                                               __bf16* __restrict__ ao) {
    __shared__ __bf16 Ps[80][64];
    __shared__ __bf16 Vs[64][64];
    const int bh = blockIdx.x, b = bh >> 4, h = bh & 15;
    const int t = threadIdx.x, wid = t >> 6, lane = t & 63;
    const int lrow = lane & 15;
    const __bf16* pbase = sp + (size_t)bh * LTOT * KPAD;
    const __bf16* vbase = vt + (size_t)bh * DH * KPAD;
    const bf16x8 zero8 = {};
    f32x4 acc[5] = {};

    for (int kt = 0; kt < KPAD; kt += 64) {
        for (int s = t; s < 80 * 8; s += 256) {
            int r = s >> 3, c8 = s & 7;
            bf16x8 v = zero8;
            if (r < LTOT) v = *(const bf16x8*)(pbase + (size_t)r * KPAD + kt + (c8 << 3));
            *(bf16x8*)(&Ps[r][(c8 ^ (r & 7)) << 3]) = v;
        }
        for (int s = t; s < 64 * 8; s += 256) {
            int r = s >> 3, c8 = s & 7;
            bf16x8 v = *(const bf16x8*)(vbase + (size_t)r * KPAD + kt + (c8 << 3));
            *(bf16x8*)(&Vs[r][(c8 ^ (r & 7)) << 3]) = v;
        }
        __syncthreads();
#pragma unroll
        for (int kc = 0; kc < 2; ++kc) {
            const int ck = (kc << 2) + (lane >> 4);
            int rb = wid * 16 + lrow;
            bf16x8 bfr = *(const bf16x8*)(&Vs[rb][(ck ^ (rb & 7)) << 3]);
#pragma unroll
            for (int fm = 0; fm < 5; ++fm) {
                int ra = fm * 16 + lrow;
                bf16x8 af = *(const bf16x8*)(&Ps[ra][(ck ^ (ra & 7)) << 3]);
                acc[fm] = __builtin_amdgcn_mfma_f32_16x16x32_bf16(
                    af, bfr, acc[fm], 0, 0, 0);
            }
        }
        __syncthreads();
    }
    __bf16* obase = ao + (size_t)b * LTOT * DIM + h * DH;
    const int rbase = (lane >> 4) << 2, cofs = lane & 15;
#pragma unroll
    for (int fm = 0; fm < 5; ++fm)
#pragma unroll
        for (int j = 0; j < 4; ++j) {
            int r = fm * 16 + rbase + j;
            if (r >= LTOT) continue;
            obase[(size_t)r * DIM + wid * 16 + cofs] = f2bf(acc[fm][j]);
        }
}

// ---------------------------------------------------------------------------
template <int EPI, bool POW2>
static void g128(const __bf16* A, const __bf16* Bt, void* C0, void* C1,
                 const float* bias, int M, int N, int K, int lda, int ldb,
                 int brs, long long bs, int ldc, float scale, int gz, int az,
                 long long cz, int zhalf, hipStream_t s) {
    dim3 g(N / 128, (M + 127) / 128, gz);
    gemm_bf16<EPI, POW2><<<g, 256, 0, s>>>(A, Bt, C0, C1, bias, M, N, K, lda,
                                           ldb, brs, bs, ldc, scale, az, cz,
                                           zhalf);
}

extern "C" void kernel_launch(void* const* d_in, const int* in_sizes, int n_in,
                              void* d_out, int out_size, void* d_ws, size_t ws_size,
                              hipStream_t stream) {
    (void)in_sizes; (void)n_in; (void)out_size; (void)ws_size;
    const float* x          = (const float*)d_in[0];
    const float* pos_emb    = (const float*)d_in[2];
    const float* latents    = (const float*)d_in[3];
    const float* mp_ln_g    = (const float*)d_in[4];
    const float* mp_w       = (const float*)d_in[5];
    const float* mp_b       = (const float*)d_in[6];
    const float* attn_norm_w= (const float*)d_in[7];
    const float* attn_norm_b= (const float*)d_in[8];
    const float* attn_lat_w = (const float*)d_in[9];
    const float* attn_lat_b = (const float*)d_in[10];
    const float* Wq         = (const float*)d_in[11];
    const float* Wkv        = (const float*)d_in[12];
    const float* Wout       = (const float*)d_in[13];
    const float* out_ln_w   = (const float*)d_in[14];
    const float* out_ln_b   = (const float*)d_in[15];
    const float* ff_ln1_g   = (const float*)d_in[16];
    const float* ff_w1      = (const float*)d_in[17];
    const float* ff_ln2_g   = (const float*)d_in[18];
    const float* ff_w2      = (const float*)d_in[19];

    float* lat = (float*)d_out;                    // residual stream, f32

    char* ws = (char*)d_ws;
    size_t off = 0;
    auto take = [&](size_t bytes) -> char* {
        char* p = ws + off;
        off += (bytes + 255) & ~(size_t)255;
        return p;
    };
    __bf16* xpos = (__bf16*)take(2ULL * BATCH * SEQL * DIM);
    __bf16* xn   = (__bf16*)take(2ULL * BATCH * SEQL * DIM);
    __bf16* lnl  = (__bf16*)take(2ULL * BATCH * LTOT * DIM);
    __bf16* ffin = (__bf16*)take(2ULL * BATCH * LTOT * DIM);
    __bf16* qb   = (__bf16*)take(2ULL * BATCH * LTOT * DIM);
    __bf16* ao   = (__bf16*)take(2ULL * BATCH * LTOT * DIM);
    __bf16* kvb  = (__bf16*)take(2ULL * BATCH * KEYS * 2048);
    float*  gout = (float*)take(4ULL * MLAT * HID);           // 35.65 MB scratch
    __bf16* h2   = (__bf16*)take(2ULL * MLAT * HID);          // 17.8 MB (contig)
    __bf16* vt   = (__bf16*)take(2ULL * BATCH * HEADS * DH * KPAD);  // 41.9 MB
    __bf16* wT   = (__bf16*)take(2ULL * 12 * 1024 * 1024);
    float*  pooled = (float*)take(4ULL * BATCH * DIM);
    __bf16* mpin = (__bf16*)take(2ULL * BATCH * DIM);

    // overlays (time-disjoint):
    //  sp  = attention scores (qk..pv), bf16, 44.6 MB in gout..h2
    //  gk  = q+kvtail bf16 partial slabs (2 x 13.4 MB) in gout
    //  ff1 partials: 2 bf16 slabs x 17.8 MB in gout ; ff2: 8 x 4.45 MB in gout
    //  wout partials: 4 bf16 slabs x 4.45 MB in vt (dead after pv)
    __bf16* sp  = (__bf16*)gout;
    __bf16* gkb = (__bf16*)gout;

    __bf16* wqT   = wT;                    // [1024,1024]
    __bf16* wkvT  = wT + 1 * 1024 * 1024;  // [2048,1024] (contig after wqT)
    __bf16* woutT = wT + 3 * 1024 * 1024;  // [1024,1024]
    __bf16* f1T   = wT + 4 * 1024 * 1024;  // [4096,1024]
    __bf16* f2T   = wT + 8 * 1024 * 1024;  // [1024,4096]
    __bf16* mpwT  = wT;                    // [4096,1024], used before layers

    // ---- prologue -----------------------------------------------------
    add_pos<<<4096, 256, 0, stream>>>(x, pos_emb, xpos);
    pool_mean<<<128, 256, 0, stream>>>(x, pooled);
    ln_rows<float, false, DIM><<<BATCH, 256, 0, stream>>>(pooled, mpin, mp_ln_g, nullptr);
    transpose_cast<<<dim3(128, 32), 256, 0, stream>>>(mp_w, mpwT, 1024, 4096);
    g128<0, true>(mpin, mpwT, lat, lat, mp_b, BATCH, 4096, 1024, 1024, 1024,
                  5, 0, LTOT * DIM, 1.f, 1, 0, 0, 1, stream);
    lat_fill<<<2048, 256, 0, stream>>>(latents, lat);

    // ---- layers -------------------------------------------------------
    for (int i = 0; i < 4; ++i) {
        transpose_all<<<12288, 256, 0, stream>>>(
            Wq + (size_t)i * 1024 * 1024, Wkv + (size_t)i * 1024 * 2048,
            Wout + (size_t)i * 1024 * 1024, ff_w1 + (size_t)i * 1024 * 4096,
            ff_w2 + (size_t)i * 4096 * 1024,
            wqT, wkvT, woutT, f1T, f2T);

        ln_rows<__bf16, true, DIM><<<BATCH * SEQL, 256, 0, stream>>>(
            xpos, xn, attn_norm_w + i * DIM, attn_norm_b + i * DIM);
        ln_rows<float, true, DIM><<<BATCH * LTOT, 256, 0, stream>>>(
            lat, lnl, attn_lat_w + i * DIM, attn_lat_b + i * DIM);

        // q + kv-tail: lnl @ [Wq|Wkv] (N=3072), split-K x2, bf16 partials
        g128<1, true>(lnl, wqT, gkb, gkb, nullptr, MLAT, 3072, 512, 1024, 1024,
                      31, 0, 3072, 1.f, 2, 512, (long long)MLAT * 3072, 2, stream);
        qkv_red<<<dim3(3, MLAT), 256, 0, stream>>>(gkb, qb, kvb);

        // kv rows 0..511 per batch from xn (256x256 8-phase kernel)
        gemm256<1><<<dim3(512), 512, 0, stream>>>(
            xn, wkvT, kvb, nullptr, BATCH * SEQL, 2048, 1024,
            9, (long long)KEYS * 2048, 2048, 1.f, 3);

        // ---- MFMA attention ----
        vt_tr<<<dim3(BATCH * HEADS, KPAD / 32, 2), 256, 0, stream>>>(kvb, vt);
        qk_gemm<<<dim3(BATCH * HEADS, KPAD / 128), 256, 0, stream>>>(qb, kvb, sp);
        softmax_p<<<(BATCH * HEADS * LTOT) / 4, 256, 0, stream>>>(sp);
        pv_gemm<<<BATCH * HEADS, 256, 0, stream>>>(sp, vt, ao);

        // wout split-K x4 -> 4 bf16 slabs in vt (free after pv)
        g128<1, true>(ao, woutT, vt, vt, nullptr, MLAT, 1024, 256, 1024, 1024,
                      31, 0, 1024, 1.f, 4, 256, (long long)MLAT * 1024, 4, stream);
        wout_ln_res<<<BATCH * LTOT, 256, 0, stream>>>(
            vt, lat, ffin, out_ln_w + i * DIM, out_ln_b + i * DIM, ff_ln1_g + i * DIM);

        // ff1 split-K x2 -> 2 bf16 slabs in gout (sp dead)
        g128<1, true>(ffin, f1T, gkb, gkb, nullptr, MLAT, HID, 512, 1024, 1024,
                      31, 0, HID, 1.f, 2, 512, (long long)MLAT * HID, 2, stream);
        // reduce + gelu + custom LN -> h2
        ln_gelu2<<<BATCH * LTOT, 256, 0, stream>>>(gkb, h2, ff_ln2_g + i * HID);

        // ff2 split-K x8 -> 8 bf16 slabs in gout (ff1 partials consumed)
        g128<1, true>(h2, f2T, gkb, gkb, nullptr, MLAT, 1024, 512, HID, HID,
                      31, 0, 1024, 1.f, 8, 512, (long long)MLAT * 1024, 8, stream);
        splitk_add8<<<MLAT, 256, 0, stream>>>(gkb, lat);
    }
}